// Round 1
// baseline (3535.268 us; speedup 1.0000x reference)
//
#include <hip/hip_runtime.h>
#include <hip/hip_bf16.h>

typedef __hip_bfloat16 bf16;
typedef __attribute__((ext_vector_type(8))) short short8;
typedef __attribute__((ext_vector_type(4))) float f32x4;

#define DEVINL static __device__ __forceinline__

DEVINL float b2f(bf16 x) { return __bfloat162float(x); }
DEVINL bf16 f2b(float x) { return __float2bfloat16(x); }

DEVINL void gload16(const void* g, void* l) {
  __builtin_amdgcn_global_load_lds(
      (const __attribute__((address_space(1))) void*)g,
      (__attribute__((address_space(3))) void*)l, 16, 0, 0);
}

DEVINL float wave_sum(float v) {
#pragma unroll
  for (int o = 32; o > 0; o >>= 1) v += __shfl_down(v, o, 64);
  return v;
}

DEVINL float block_sum256(float v, float* red4) {
  v = wave_sum(v);
  __syncthreads();
  if ((threadIdx.x & 63) == 0) red4[threadIdx.x >> 6] = v;
  __syncthreads();
  return red4[0] + red4[1] + red4[2] + red4[3];
}

// ---------------------------------------------------------------------------
// Generic NT GEMM: C[M,N] = sum_k A[m,k]*B[n,k]; A,B bf16 row-major.
// MODE 0: store bf16            MODE 1: exact-erf GELU, store bf16
// MODE 2: outf = resf + acc (fp32)
// MODE 3: split-write hi/lo bf16 (NS gram matrix)
// MODE 4: v = alpha*Xf + beta*acc; update Xf + hi/lo + transposed hi/lo
// SPLIT: A/B given as hi+lo bf16 pairs; acc = Ah*Bh + Ah*Bl + Al*Bh.
// Tiles: 128x128, BK=32, 256 threads (4 waves, each 64x64 via 4x4 mfma 16x16x32)
// LDS layout per tile: [4 chunks][128 rows][8 bf16] -> ds_read_b128 friendly.
// ---------------------------------------------------------------------------
template <int MODE, bool SPLIT>
__global__ __launch_bounds__(256) void gemm_nt(
    const bf16* __restrict__ A0, const bf16* __restrict__ A1,
    const bf16* __restrict__ B0, const bf16* __restrict__ B1,
    int K, int lda, int ldb, long bsA, long bsB, long bsC,
    bf16* __restrict__ outb, int ldo,
    const float* __restrict__ resf, float* __restrict__ outf,
    float alpha, float beta, float* __restrict__ Xf,
    bf16* __restrict__ Whi, bf16* __restrict__ Wlo,
    bf16* __restrict__ Thi, bf16* __restrict__ Tlo) {
  extern __shared__ char smem[];
  bf16* AsH = (bf16*)smem;        // 4096 elems = 8KB
  bf16* BsH = AsH + 4096;
  bf16* AsL = BsH + 4096;         // only with SPLIT (32KB dynamic LDS)
  bf16* BsL = AsL + 4096;

  const int t = threadIdx.x;
  const int lane = t & 63, w = t >> 6;
  const long bz = blockIdx.z;
  const bf16* Ab0 = A0 + bz * bsA;
  const bf16* Bb0 = B0 + bz * bsB;
  const bf16* Ab1 = SPLIT ? (A1 + bz * bsA) : nullptr;
  const bf16* Bb1 = SPLIT ? (B1 + bz * bsB) : nullptr;

  const int row0 = blockIdx.y * 128, col0 = blockIdx.x * 128;
  const int wm = (w >> 1) * 64, wn = (w & 1) * 64;
  const int jj = lane >> 4, r16 = lane & 15;

  f32x4 acc[4][4] = {};

  for (int k0 = 0; k0 < K; k0 += 32) {
    __syncthreads();
#pragma unroll
    for (int s = 0; s < 2; ++s) {
      const int L = s * 256 + t;
      const int cj = L >> 7, m = L & 127;
      const long ga = (long)(row0 + m) * lda + (k0 + cj * 8);
      const long gb = (long)(col0 + m) * ldb + (k0 + cj * 8);
      gload16(Ab0 + ga, AsH + L * 8);
      gload16(Bb0 + gb, BsH + L * 8);
      if (SPLIT) {
        gload16(Ab1 + ga, AsL + L * 8);
        gload16(Bb1 + gb, BsL + L * 8);
      }
    }
    __syncthreads();

    short8 a[4], b[4], al[4], bl[4];
#pragma unroll
    for (int mt = 0; mt < 4; ++mt) {
      const int o = jj * 1024 + (wm + mt * 16 + r16) * 8;
      a[mt] = *(const short8*)(AsH + o);
      if (SPLIT) al[mt] = *(const short8*)(AsL + o);
    }
#pragma unroll
    for (int nt = 0; nt < 4; ++nt) {
      const int o = jj * 1024 + (wn + nt * 16 + r16) * 8;
      b[nt] = *(const short8*)(BsH + o);
      if (SPLIT) bl[nt] = *(const short8*)(BsL + o);
    }
#pragma unroll
    for (int mt = 0; mt < 4; ++mt)
#pragma unroll
      for (int nt = 0; nt < 4; ++nt) {
        acc[mt][nt] = __builtin_amdgcn_mfma_f32_16x16x32_bf16(a[mt], b[nt], acc[mt][nt], 0, 0, 0);
        if (SPLIT) {
          acc[mt][nt] = __builtin_amdgcn_mfma_f32_16x16x32_bf16(a[mt], bl[nt], acc[mt][nt], 0, 0, 0);
          acc[mt][nt] = __builtin_amdgcn_mfma_f32_16x16x32_bf16(al[mt], b[nt], acc[mt][nt], 0, 0, 0);
        }
      }
  }

#pragma unroll
  for (int mt = 0; mt < 4; ++mt)
#pragma unroll
    for (int nt = 0; nt < 4; ++nt)
#pragma unroll
      for (int r = 0; r < 4; ++r) {
        const int row = row0 + wm + mt * 16 + jj * 4 + r;
        const int col = col0 + wn + nt * 16 + r16;
        const float v = acc[mt][nt][r];
        if (MODE == 0) {
          outb[bz * bsC + (long)row * ldo + col] = f2b(v);
        } else if (MODE == 1) {
          const float g = 0.5f * v * (1.0f + erff(v * 0.70710678118654752f));
          outb[(long)row * ldo + col] = f2b(g);
        } else if (MODE == 2) {
          const long i = (long)row * ldo + col;
          outf[i] = resf[i] + v;
        } else if (MODE == 3) {
          const long i = bz * bsC + (long)row * 512 + col;
          const bf16 h = f2b(v);
          Whi[i] = h;
          Wlo[i] = f2b(v - b2f(h));
        } else if (MODE == 4) {
          const long i = bz * bsC + (long)row * 512 + col;
          const float nv = alpha * Xf[i] + beta * v;
          Xf[i] = nv;
          const bf16 h = f2b(nv);
          const bf16 l = f2b(nv - b2f(h));
          Whi[i] = h; Wlo[i] = l;
          const long it2 = bz * bsC + (long)col * 512 + row;
          Thi[it2] = h; Tlo[it2] = l;
        }
      }
}

// ---------------------------------------------------------------------------
// Power iteration for sigma_max of 512x512 W (one block per matrix).
// ---------------------------------------------------------------------------
__global__ __launch_bounds__(256) void pow_iter(const float* __restrict__ W1,
                                                const float* __restrict__ W2,
                                                float* __restrict__ sig) {
  __shared__ float v[512], u[512];
  __shared__ float red4[4];
  const float* W = (blockIdx.x == 0) ? W1 : W2;
  const int t = threadIdx.x;
  v[t] = 1.0f + 0.001f * (float)((t * 37) & 63);
  v[t + 256] = 1.0f + 0.001f * (float)(((t + 256) * 37) & 63);
  __syncthreads();
  float sigma = 1.0f;
  for (int it = 0; it < 12; ++it) {
    for (int h = 0; h < 2; ++h) {
      const int r = t + h * 256;
      const float* row = W + (long)r * 512;
      float s = 0.f;
      for (int c = 0; c < 512; ++c) s += row[c] * v[c];
      u[r] = s;
    }
    __syncthreads();
    float nu2 = block_sum256(u[t] * u[t] + u[t + 256] * u[t + 256], red4);
    float inv = rsqrtf(nu2 + 1e-30f);
    u[t] *= inv; u[t + 256] *= inv;
    __syncthreads();
    float nvt[2];
    for (int h = 0; h < 2; ++h) {
      const int c = t + h * 256;
      float s = 0.f;
      for (int r = 0; r < 512; ++r) s += W[(long)r * 512 + c] * u[r];
      nvt[h] = s;
    }
    __syncthreads();
    v[t] = nvt[0]; v[t + 256] = nvt[1];
    __syncthreads();
    float nv2 = block_sum256(v[t] * v[t] + v[t + 256] * v[t + 256], red4);
    sigma = sqrtf(nv2);
    inv = rsqrtf(nv2 + 1e-30f);
    v[t] *= inv; v[t + 256] *= inv;
    __syncthreads();
  }
  if (t == 0) sig[blockIdx.x] = sigma;
}

// X0 = W / (1.05*sigma); emit fp32 master + hi/lo splits + transposed splits.
__global__ __launch_bounds__(256) void scale_init(
    const float* __restrict__ W1, const float* __restrict__ W2,
    const float* __restrict__ sig, float* __restrict__ Xf,
    bf16* __restrict__ Xhi, bf16* __restrict__ Xlo,
    bf16* __restrict__ Thi, bf16* __restrict__ Tlo) {
  const long idx = (long)blockIdx.x * 256 + threadIdx.x;  // 2*262144 total
  const int b = (int)(idx >> 18);
  const int i = (int)(idx & 262143);
  const float s = 1.0f / (1.05f * sig[b]);
  const float val = (b ? W2[i] : W1[i]) * s;
  const long o = ((long)b << 18) + i;
  Xf[o] = val;
  const bf16 h = f2b(val);
  const bf16 l = f2b(val - b2f(h));
  Xhi[o] = h; Xlo[o] = l;
  const int r = i >> 9, c = i & 511;
  const long ot = ((long)b << 18) + (long)c * 512 + r;
  Thi[ot] = h; Tlo[ot] = l;
}

__global__ __launch_bounds__(256) void f32_to_b16(const float* __restrict__ in,
                                                  bf16* __restrict__ out, int n) {
  const int i = blockIdx.x * 256 + threadIdx.x;
  if (i < n) out[i] = f2b(in[i]);
}

// LayerNorm over C=512 (one block per row), bf16 out.
__global__ __launch_bounds__(256) void ln_rows(const float* __restrict__ x,
                                               const float* __restrict__ w,
                                               bf16* __restrict__ out) {
  __shared__ float red4[4];
  const long row = blockIdx.x;
  const int t = threadIdx.x;
  const float a = x[row * 512 + t];
  const float b = x[row * 512 + t + 256];
  const float mean = block_sum256(a + b, red4) * (1.0f / 512.0f);
  const float msq = block_sum256(a * a + b * b, red4) * (1.0f / 512.0f);
  const float var = msq - mean * mean;
  const float inv = rsqrtf(var + 1e-5f);
  out[row * 512 + t] = f2b((a - mean) * inv * w[t]);
  out[row * 512 + t + 256] = f2b((b - mean) * inv * w[t + 256]);
}

// pscan combine: q[t] = rmsnorm(Y[t-d] + Z[t]) for t >= d (per batch).
// YZ is [16384][1024] bf16 (Y cols 0..511, Z cols 512..1023); q = QV cols 0..511.
__global__ __launch_bounds__(256) void pscan_combine(const bf16* __restrict__ YZ,
                                                     bf16* __restrict__ QV, int d) {
  __shared__ float red4[4];
  const int span = 4096 - d;
  const int idx = blockIdx.x;
  const int b = idx / span;
  const int tt = d + (idx - b * span);
  const long rowQ = (long)b * 4096 + tt;
  const bf16* Yr = YZ + (rowQ - d) * 1024;
  const bf16* Zr = YZ + rowQ * 1024 + 512;
  const int t = threadIdx.x;
  const float z0 = b2f(Yr[2 * t]) + b2f(Zr[2 * t]);
  const float z1 = b2f(Yr[2 * t + 1]) + b2f(Zr[2 * t + 1]);
  const float ss = block_sum256(z0 * z0 + z1 * z1, red4);
  const float inv = rsqrtf(ss * (1.0f / 512.0f) + 1e-6f);
  QV[rowQ * 1024 + 2 * t] = f2b(z0 * inv);
  QV[rowQ * 1024 + 2 * t + 1] = f2b(z1 * inv);
}

// u = q * v elementwise (q = QV cols 0..511, v = QV cols 512..1023).
__global__ __launch_bounds__(256) void qv_mul(const bf16* __restrict__ QV,
                                              bf16* __restrict__ u) {
  const long idx = (long)blockIdx.x * 256 + threadIdx.x;
  const long row = idx >> 9;
  const int c = (int)(idx & 511);
  u[idx] = f2b(b2f(QV[row * 1024 + c]) * b2f(QV[row * 1024 + 512 + c]));
}

// ---------------------------------------------------------------------------
extern "C" void kernel_launch(void* const* d_in, const int* in_sizes, int n_in,
                              void* d_out, int out_size, void* d_ws, size_t ws_size,
                              hipStream_t stream) {
  (void)in_sizes; (void)n_in; (void)out_size; (void)ws_size;
  const float* x    = (const float*)d_in[0];
  const float* ln1w = (const float*)d_in[1];
  const float* Wq   = (const float*)d_in[2];
  const float* Wv   = (const float*)d_in[3];
  const float* Wo   = (const float*)d_in[4];
  // d_in[5] = identity: provably unused (positions t<d are never updated)
  const float* Wp1  = (const float*)d_in[6];
  const float* Wp2  = (const float*)d_in[7];
  const float* ln2w = (const float*)d_in[8];
  const float* Wfc  = (const float*)d_in[9];
  const float* Wpr  = (const float*)d_in[10];
  float* out = (float*)d_out;

  const long M = 16384;
  char* ws = (char*)d_ws;
  size_t off = 0;
  auto alloc = [&](size_t bytes) -> void* {
    void* p = ws + off;
    off += (bytes + 255) & ~(size_t)255;
    return p;
  };
  bf16* YZ   = (bf16*)alloc(M * 1024 * 2);   // 32MB; YZ+QV contiguous -> reused as h3 (64MB)
  bf16* QV   = (bf16*)alloc(M * 1024 * 2);   // 32MB
  bf16* hb   = (bf16*)alloc(M * 512 * 2);    // h -> u -> h2
  bf16* Wqvb = (bf16*)alloc(1024 * 512 * 2);
  bf16* Wob  = (bf16*)alloc(512 * 512 * 2);
  bf16* Wfcb = (bf16*)alloc(2048 * 512 * 2);
  bf16* Wprb = (bf16*)alloc(512 * 2048 * 2);
  float* Xf  = (float*)alloc(2 * 262144 * 4);
  bf16* Xhi  = (bf16*)alloc(2 * 262144 * 2);  // final P1;P2 bf16 (pscan B matrix)
  bf16* Xlo  = (bf16*)alloc(2 * 262144 * 2);
  bf16* XtAh = (bf16*)alloc(2 * 262144 * 2);
  bf16* XtAl = (bf16*)alloc(2 * 262144 * 2);
  bf16* XtBh = (bf16*)alloc(2 * 262144 * 2);
  bf16* XtBl = (bf16*)alloc(2 * 262144 * 2);
  bf16* Ghi  = (bf16*)alloc(2 * 262144 * 2);
  bf16* Glo  = (bf16*)alloc(2 * 262144 * 2);
  float* sig = (float*)alloc(256);
  bf16* h3 = YZ;  // [16384,2048] bf16 spans YZ+QV (both dead by then)

  // --- polar decomposition of Wp1, Wp2 (batched Newton-Schulz, split-bf16 MFMA)
  pow_iter<<<2, 256, 0, stream>>>(Wp1, Wp2, sig);
  scale_init<<<2048, 256, 0, stream>>>(Wp1, Wp2, sig, Xf, Xhi, Xlo, XtAh, XtAl);

  bf16 *tch = XtAh, *tcl = XtAl, *tnh = XtBh, *tnl = XtBl;
  const long S = 262144;
  for (int i = 0; i < 24; ++i) {
    const bool std = (i == 0 || i >= 18);
    const float ac = std ? 1.5f : 2.0f;
    const float bc = std ? -0.5f : -1.0f;
    dim3 g(4, 4, 2);
    // G = X X^T
    gemm_nt<3, true><<<g, 256, 32768, stream>>>(
        Xhi, Xlo, Xhi, Xlo, 512, 512, 512, S, S, S,
        nullptr, 0, nullptr, nullptr, 0.f, 0.f, nullptr, Ghi, Glo, nullptr, nullptr);
    // X = a*X + b*G*X   (B-operand = X^T splits)
    gemm_nt<4, true><<<g, 256, 32768, stream>>>(
        Ghi, Glo, tch, tcl, 512, 512, 512, S, S, S,
        nullptr, 0, nullptr, nullptr, ac, bc, Xf, Xhi, Xlo, tnh, tnl);
    bf16* sw;
    sw = tch; tch = tnh; tnh = sw;
    sw = tcl; tcl = tnl; tnl = sw;
  }

  // --- weight conversions to bf16
  f32_to_b16<<<1024, 256, 0, stream>>>(Wq, Wqvb, 262144);
  f32_to_b16<<<1024, 256, 0, stream>>>(Wv, Wqvb + 262144, 262144);
  f32_to_b16<<<1024, 256, 0, stream>>>(Wo, Wob, 262144);
  f32_to_b16<<<4096, 256, 0, stream>>>(Wfc, Wfcb, 1048576);
  f32_to_b16<<<4096, 256, 0, stream>>>(Wpr, Wprb, 1048576);

  // --- SSM branch
  ln_rows<<<M, 256, 0, stream>>>(x, ln1w, hb);
  // [q|v] = h @ [Wq;Wv]^T
  gemm_nt<0, false><<<dim3(8, 128, 1), 256, 16384, stream>>>(
      hb, nullptr, Wqvb, nullptr, 512, 512, 512, 0, 0, 0,
      QV, 1024, nullptr, nullptr, 0.f, 0.f, nullptr, nullptr, nullptr, nullptr, nullptr);

  for (int d = 1; d < 4096; d <<= 1) {
    // YZ = q @ [P1;P2]^T  (q = QV cols 0..511, lda 1024)
    gemm_nt<0, false><<<dim3(8, 128, 1), 256, 16384, stream>>>(
        QV, nullptr, Xhi, nullptr, 512, 1024, 512, 0, 0, 0,
        YZ, 1024, nullptr, nullptr, 0.f, 0.f, nullptr, nullptr, nullptr, nullptr, nullptr);
    pscan_combine<<<4 * (4096 - d), 256, 0, stream>>>(YZ, QV, d);
  }

  qv_mul<<<(int)(M * 512 / 256), 256, 0, stream>>>(QV, hb);  // u -> hb
  // x2 = x + u @ Wo^T  -> d_out (fp32)
  gemm_nt<2, false><<<dim3(4, 128, 1), 256, 16384, stream>>>(
      hb, nullptr, Wob, nullptr, 512, 512, 512, 0, 0, 0,
      nullptr, 512, x, out, 0.f, 0.f, nullptr, nullptr, nullptr, nullptr, nullptr);

  // --- MLP branch
  ln_rows<<<M, 256, 0, stream>>>(out, ln2w, hb);  // h2 -> hb
  gemm_nt<1, false><<<dim3(16, 128, 1), 256, 16384, stream>>>(
      hb, nullptr, Wfcb, nullptr, 512, 512, 512, 0, 0, 0,
      h3, 2048, nullptr, nullptr, 0.f, 0.f, nullptr, nullptr, nullptr, nullptr, nullptr);
  gemm_nt<2, false><<<dim3(4, 128, 1), 256, 16384, stream>>>(
      h3, nullptr, Wprb, nullptr, 2048, 2048, 2048, 0, 0, 0,
      nullptr, 512, out, out, 0.f, 0.f, nullptr, nullptr, nullptr, nullptr, nullptr);
}

// Round 3
// 3186.445 us; speedup vs baseline: 1.1095x; 1.1095x over previous
//
#include <hip/hip_runtime.h>
#include <hip/hip_bf16.h>

typedef __hip_bfloat16 bf16;
typedef __attribute__((ext_vector_type(8))) short short8;
typedef __attribute__((ext_vector_type(4))) short short4v;
typedef __attribute__((ext_vector_type(4))) float f32x4;

#define DEVINL static __device__ __forceinline__

DEVINL float b2f(bf16 x) { return __bfloat162float(x); }
DEVINL bf16 f2b(float x) { return __float2bfloat16(x); }
DEVINL float sb2f(short s) { return b2f(__builtin_bit_cast(bf16, s)); }
DEVINL short f2sb(float x) { return __builtin_bit_cast(short, f2b(x)); }

DEVINL void gload16(const void* g, void* l) {
  __builtin_amdgcn_global_load_lds(
      (const __attribute__((address_space(1))) void*)g,
      (__attribute__((address_space(3))) void*)l, 16, 0, 0);
}

DEVINL float wave_sum(float v) {
#pragma unroll
  for (int o = 32; o > 0; o >>= 1) v += __shfl_down(v, o, 64);
  return v;
}

DEVINL float wave_allsum(float v) {
#pragma unroll
  for (int o = 32; o > 0; o >>= 1) v += __shfl_xor(v, o, 64);
  return v;
}

// ---------------------------------------------------------------------------
// Generic NT GEMM: C[M,N] = sum_k A[m,k]*B[n,k]; A,B bf16 row-major.
// MODE 0: store bf16            MODE 1: exact-erf GELU, store bf16
// MODE 2: outf = resf + acc (fp32)
// MODE 3: split-write hi/lo bf16 (NS gram matrix)
// MODE 4: v = alpha*Xf + beta*acc; update Xf + hi/lo + transposed hi/lo
// SPLIT: A/B given as hi+lo bf16 pairs; acc = Ah*Bh + Ah*Bl + Al*Bh.
// Tiles: 128x128, BK=32, 256 threads (4 waves, each 64x64 via 4x4 mfma 16x16x32)
// LDS layout per tile: [4 chunks][128 rows][8 bf16] -> ds_read_b128 friendly.
// ---------------------------------------------------------------------------
template <int MODE, bool SPLIT>
__global__ __launch_bounds__(256) void gemm_nt(
    const bf16* __restrict__ A0, const bf16* __restrict__ A1,
    const bf16* __restrict__ B0, const bf16* __restrict__ B1,
    int K, int lda, int ldb, long bsA, long bsB, long bsC,
    bf16* __restrict__ outb, int ldo,
    const float* __restrict__ resf, float* __restrict__ outf,
    float alpha, float beta, float* __restrict__ Xf,
    bf16* __restrict__ Whi, bf16* __restrict__ Wlo,
    bf16* __restrict__ Thi, bf16* __restrict__ Tlo) {
  extern __shared__ char smem[];
  bf16* AsH = (bf16*)smem;        // 4096 elems = 8KB
  bf16* BsH = AsH + 4096;
  bf16* AsL = BsH + 4096;         // only with SPLIT (32KB dynamic LDS)
  bf16* BsL = AsL + 4096;

  const int t = threadIdx.x;
  const int lane = t & 63, w = t >> 6;
  const long bz = blockIdx.z;
  const bf16* Ab0 = A0 + bz * bsA;
  const bf16* Bb0 = B0 + bz * bsB;
  const bf16* Ab1 = SPLIT ? (A1 + bz * bsA) : nullptr;
  const bf16* Bb1 = SPLIT ? (B1 + bz * bsB) : nullptr;

  const int row0 = blockIdx.y * 128, col0 = blockIdx.x * 128;
  const int wm = (w >> 1) * 64, wn = (w & 1) * 64;
  const int jj = lane >> 4, r16 = lane & 15;

  f32x4 acc[4][4] = {};

  for (int k0 = 0; k0 < K; k0 += 32) {
    __syncthreads();
#pragma unroll
    for (int s = 0; s < 2; ++s) {
      const int L = s * 256 + t;
      const int cj = L >> 7, m = L & 127;
      const long ga = (long)(row0 + m) * lda + (k0 + cj * 8);
      const long gb = (long)(col0 + m) * ldb + (k0 + cj * 8);
      gload16(Ab0 + ga, AsH + L * 8);
      gload16(Bb0 + gb, BsH + L * 8);
      if (SPLIT) {
        gload16(Ab1 + ga, AsL + L * 8);
        gload16(Bb1 + gb, BsL + L * 8);
      }
    }
    __syncthreads();

    short8 a[4], b[4], al[4], bl[4];
#pragma unroll
    for (int mt = 0; mt < 4; ++mt) {
      const int o = jj * 1024 + (wm + mt * 16 + r16) * 8;
      a[mt] = *(const short8*)(AsH + o);
      if (SPLIT) al[mt] = *(const short8*)(AsL + o);
    }
#pragma unroll
    for (int nt = 0; nt < 4; ++nt) {
      const int o = jj * 1024 + (wn + nt * 16 + r16) * 8;
      b[nt] = *(const short8*)(BsH + o);
      if (SPLIT) bl[nt] = *(const short8*)(BsL + o);
    }
#pragma unroll
    for (int mt = 0; mt < 4; ++mt)
#pragma unroll
      for (int nt = 0; nt < 4; ++nt) {
        acc[mt][nt] = __builtin_amdgcn_mfma_f32_16x16x32_bf16(a[mt], b[nt], acc[mt][nt], 0, 0, 0);
        if (SPLIT) {
          acc[mt][nt] = __builtin_amdgcn_mfma_f32_16x16x32_bf16(a[mt], bl[nt], acc[mt][nt], 0, 0, 0);
          acc[mt][nt] = __builtin_amdgcn_mfma_f32_16x16x32_bf16(al[mt], b[nt], acc[mt][nt], 0, 0, 0);
        }
      }
  }

#pragma unroll
  for (int mt = 0; mt < 4; ++mt)
#pragma unroll
    for (int nt = 0; nt < 4; ++nt)
#pragma unroll
      for (int r = 0; r < 4; ++r) {
        const int row = row0 + wm + mt * 16 + jj * 4 + r;
        const int col = col0 + wn + nt * 16 + r16;
        const float v = acc[mt][nt][r];
        if (MODE == 0) {
          outb[bz * bsC + (long)row * ldo + col] = f2b(v);
        } else if (MODE == 1) {
          const float g = 0.5f * v * (1.0f + erff(v * 0.70710678118654752f));
          outb[(long)row * ldo + col] = f2b(g);
        } else if (MODE == 2) {
          const long i = (long)row * ldo + col;
          outf[i] = resf[i] + v;
        } else if (MODE == 3) {
          const long i = bz * bsC + (long)row * 512 + col;
          const bf16 h = f2b(v);
          Whi[i] = h;
          Wlo[i] = f2b(v - b2f(h));
        } else if (MODE == 4) {
          const long i = bz * bsC + (long)row * 512 + col;
          const float nv = alpha * Xf[i] + beta * v;
          Xf[i] = nv;
          const bf16 h = f2b(nv);
          const bf16 l = f2b(nv - b2f(h));
          Whi[i] = h; Wlo[i] = l;
          const long it2 = bz * bsC + (long)col * 512 + row;
          Thi[it2] = h; Tlo[it2] = l;
        }
      }
}

// ---------------------------------------------------------------------------
// Frobenius norm^2 of W1, W2 (512x512 each): grid 512 blocks, atomicAdd.
// sigsq must be zeroed first. ||W||_F >= sigma_max always -> safe NS scaling.
// ---------------------------------------------------------------------------
__global__ __launch_bounds__(256) void fnorm(const float* __restrict__ W1,
                                             const float* __restrict__ W2,
                                             float* __restrict__ sigsq) {
  const int b = blockIdx.x >> 8;
  const float4 v = *(const float4*)((b ? W2 : W1) +
                                    (((long)(blockIdx.x & 255) * 256 + threadIdx.x) << 2));
  float s = v.x * v.x + v.y * v.y + v.z * v.z + v.w * v.w;
  s = wave_sum(s);
  if ((threadIdx.x & 63) == 0) atomicAdd(&sigsq[b], s);
}

// X0 = W / ||W||_F; emit fp32 master + hi/lo splits + transposed splits.
__global__ __launch_bounds__(256) void scale_init(
    const float* __restrict__ W1, const float* __restrict__ W2,
    const float* __restrict__ sigsq, float* __restrict__ Xf,
    bf16* __restrict__ Xhi, bf16* __restrict__ Xlo,
    bf16* __restrict__ Thi, bf16* __restrict__ Tlo) {
  const long idx = (long)blockIdx.x * 256 + threadIdx.x;  // 2*262144 total
  const int b = (int)(idx >> 18);
  const int i = (int)(idx & 262143);
  const float s = rsqrtf(sigsq[b]);
  const float val = (b ? W2[i] : W1[i]) * s;
  const long o = ((long)b << 18) + i;
  Xf[o] = val;
  const bf16 h = f2b(val);
  const bf16 l = f2b(val - b2f(h));
  Xhi[o] = h; Xlo[o] = l;
  const int r = i >> 9, c = i & 511;
  const long ot = ((long)b << 18) + (long)c * 512 + r;
  Thi[ot] = h; Tlo[ot] = l;
}

// All five weight matrices fp32 -> bf16 in one launch (4 elems/thread).
// Total elems: 3*262144 + 2*1048576 = 2,883,584 -> 2816 blocks of 1024 elems.
__global__ __launch_bounds__(256) void convert_weights(
    const float* __restrict__ Wq, const float* __restrict__ Wv,
    const float* __restrict__ Wo, const float* __restrict__ Wfc,
    const float* __restrict__ Wpr, bf16* __restrict__ Wqvb,
    bf16* __restrict__ Wob, bf16* __restrict__ Wfcb, bf16* __restrict__ Wprb) {
  const long e = ((long)blockIdx.x * 256 + threadIdx.x) << 2;
  const float* src; bf16* dst; long off;
  if (e < 262144)       { src = Wq;  dst = Wqvb;          off = e; }
  else if (e < 524288)  { src = Wv;  dst = Wqvb + 262144; off = e - 262144; }
  else if (e < 786432)  { src = Wo;  dst = Wob;           off = e - 524288; }
  else if (e < 1835008) { src = Wfc; dst = Wfcb;          off = e - 786432; }
  else                  { src = Wpr; dst = Wprb;          off = e - 1835008; }  // e < 2883584
  const float4 v = *(const float4*)(src + off);
  short4v o4;
  o4[0] = f2sb(v.x); o4[1] = f2sb(v.y); o4[2] = f2sb(v.z); o4[3] = f2sb(v.w);
  *(short4v*)(dst + off) = o4;
}

// LayerNorm over C=512, one wave per row (4 rows/block), bf16 out.
__global__ __launch_bounds__(256) void ln_rows(const float* __restrict__ x,
                                               const float* __restrict__ w,
                                               bf16* __restrict__ out) {
  const int row = (blockIdx.x << 2) + (threadIdx.x >> 6);
  const int lane = threadIdx.x & 63;
  const float* xr = x + (long)row * 512 + lane * 8;
  const float4 a = *(const float4*)xr;
  const float4 b = *(const float4*)(xr + 4);
  float v[8] = {a.x, a.y, a.z, a.w, b.x, b.y, b.z, b.w};
  float s1 = 0.f, s2 = 0.f;
#pragma unroll
  for (int i = 0; i < 8; ++i) { s1 += v[i]; s2 += v[i] * v[i]; }
  s1 = wave_allsum(s1);
  s2 = wave_allsum(s2);
  const float mean = s1 * (1.0f / 512.0f);
  const float var = s2 * (1.0f / 512.0f) - mean * mean;
  const float inv = rsqrtf(var + 1e-5f);
  const float4 w1 = *(const float4*)(w + lane * 8);
  const float4 w2 = *(const float4*)(w + lane * 8 + 4);
  const float wv[8] = {w1.x, w1.y, w1.z, w1.w, w2.x, w2.y, w2.z, w2.w};
  short8 o8;
#pragma unroll
  for (int i = 0; i < 8; ++i) o8[i] = f2sb((v[i] - mean) * inv * wv[i]);
  *(short8*)(out + (long)row * 512 + lane * 8) = o8;
}

// pscan combine: q[t] = rmsnorm(Y[t-d] + Z[t]) for t >= d; one wave per row.
// YZ is [16384][1024] bf16 (Y cols 0..511, Z cols 512..1023); q = QV cols 0..511.
__global__ __launch_bounds__(256) void pscan_combine(const bf16* __restrict__ YZ,
                                                     bf16* __restrict__ QV, int d) {
  const int span = 4096 - d;
  const int wid = (blockIdx.x << 2) + (threadIdx.x >> 6);  // grid = span blocks
  const int lane = threadIdx.x & 63;
  const int b = wid / span;
  const int tt = d + (wid - b * span);
  const long rowQ = (long)b * 4096 + tt;
  const short8 y8 = *(const short8*)(YZ + (rowQ - d) * 1024 + lane * 8);
  const short8 z8 = *(const short8*)(YZ + rowQ * 1024 + 512 + lane * 8);
  float s[8]; float ss = 0.f;
#pragma unroll
  for (int i = 0; i < 8; ++i) {
    const float v = sb2f(y8[i]) + sb2f(z8[i]);
    s[i] = v; ss += v * v;
  }
  ss = wave_allsum(ss);
  const float inv = rsqrtf(ss * (1.0f / 512.0f) + 1e-6f);
  short8 o8;
#pragma unroll
  for (int i = 0; i < 8; ++i) o8[i] = f2sb(s[i] * inv);
  *(short8*)(QV + rowQ * 1024 + lane * 8) = o8;
}

// u = q * v elementwise, 8 elems/thread.
__global__ __launch_bounds__(256) void qv_mul(const bf16* __restrict__ QV,
                                              bf16* __restrict__ u) {
  const long base = ((long)blockIdx.x * 256 + threadIdx.x) << 3;
  const long row = base >> 9;
  const int c = (int)(base & 511);
  const short8 q8 = *(const short8*)(QV + row * 1024 + c);
  const short8 v8 = *(const short8*)(QV + row * 1024 + 512 + c);
  short8 o8;
#pragma unroll
  for (int i = 0; i < 8; ++i) o8[i] = f2sb(sb2f(q8[i]) * sb2f(v8[i]));
  *(short8*)(u + row * 512 + c) = o8;
}

// ---------------------------------------------------------------------------
extern "C" void kernel_launch(void* const* d_in, const int* in_sizes, int n_in,
                              void* d_out, int out_size, void* d_ws, size_t ws_size,
                              hipStream_t stream) {
  (void)in_sizes; (void)n_in; (void)out_size; (void)ws_size;
  const float* x    = (const float*)d_in[0];
  const float* ln1w = (const float*)d_in[1];
  const float* Wq   = (const float*)d_in[2];
  const float* Wv   = (const float*)d_in[3];
  const float* Wo   = (const float*)d_in[4];
  // d_in[5] = identity: provably unused (positions t<d are never updated)
  const float* Wp1  = (const float*)d_in[6];
  const float* Wp2  = (const float*)d_in[7];
  const float* ln2w = (const float*)d_in[8];
  const float* Wfc  = (const float*)d_in[9];
  const float* Wpr  = (const float*)d_in[10];
  float* out = (float*)d_out;

  const long M = 16384;
  char* ws = (char*)d_ws;
  size_t off = 0;
  auto alloc = [&](size_t bytes) -> void* {
    void* p = ws + off;
    off += (bytes + 255) & ~(size_t)255;
    return p;
  };
  bf16* YZ   = (bf16*)alloc(M * 1024 * 2);   // 32MB; YZ+QV contiguous -> reused as h3 (64MB)
  bf16* QV   = (bf16*)alloc(M * 1024 * 2);   // 32MB
  bf16* hb   = (bf16*)alloc(M * 512 * 2);    // h -> u -> h2
  bf16* Wqvb = (bf16*)alloc(1024 * 512 * 2);
  bf16* Wob  = (bf16*)alloc(512 * 512 * 2);
  bf16* Wfcb = (bf16*)alloc(2048 * 512 * 2);
  bf16* Wprb = (bf16*)alloc(512 * 2048 * 2);
  float* Xf  = (float*)alloc(2 * 262144 * 4);
  bf16* Xhi  = (bf16*)alloc(2 * 262144 * 2);  // final P1;P2 bf16 (pscan B matrix)
  bf16* Xlo  = (bf16*)alloc(2 * 262144 * 2);
  bf16* XtAh = (bf16*)alloc(2 * 262144 * 2);
  bf16* XtAl = (bf16*)alloc(2 * 262144 * 2);
  bf16* XtBh = (bf16*)alloc(2 * 262144 * 2);
  bf16* XtBl = (bf16*)alloc(2 * 262144 * 2);
  bf16* Ghi  = (bf16*)alloc(2 * 262144 * 2);
  bf16* Glo  = (bf16*)alloc(2 * 262144 * 2);
  float* sig = (float*)alloc(256);
  bf16* h3 = YZ;  // [16384,2048] bf16 spans YZ+QV (both dead by then)

  // --- polar decomposition of Wp1, Wp2 (batched Newton-Schulz, split-bf16 MFMA)
  // sigma estimate: Frobenius norm (>= sigma_max, ~11x over for these inputs;
  // compensated by 4 extra doubling iterations — replaces 527us pow_iter).
  hipMemsetAsync(sig, 0, 2 * sizeof(float), stream);
  fnorm<<<512, 256, 0, stream>>>(Wp1, Wp2, sig);
  scale_init<<<2048, 256, 0, stream>>>(Wp1, Wp2, sig, Xf, Xhi, Xlo, XtAh, XtAl);

  bf16 *tch = XtAh, *tcl = XtAl, *tnh = XtBh, *tnl = XtBl;
  const long S = 262144;
  for (int i = 0; i < 27; ++i) {
    const bool pol = (i >= 21);          // 21 aggressive doublings + 6 polish
    const float ac = pol ? 1.5f : 2.0f;
    const float bc = pol ? -0.5f : -1.0f;
    dim3 g(4, 4, 2);
    // G = X X^T
    gemm_nt<3, true><<<g, 256, 32768, stream>>>(
        Xhi, Xlo, Xhi, Xlo, 512, 512, 512, S, S, S,
        nullptr, 0, nullptr, nullptr, 0.f, 0.f, nullptr, Ghi, Glo, nullptr, nullptr);
    // X = a*X + b*G*X   (B-operand = X^T splits)
    gemm_nt<4, true><<<g, 256, 32768, stream>>>(
        Ghi, Glo, tch, tcl, 512, 512, 512, S, S, S,
        nullptr, 0, nullptr, nullptr, ac, bc, Xf, Xhi, Xlo, tnh, tnl);
    bf16* sw;
    sw = tch; tch = tnh; tnh = sw;
    sw = tcl; tcl = tnl; tnl = sw;
  }

  // --- weight conversions to bf16 (one launch, 2816*1024 = 2,883,584 elems)
  convert_weights<<<2816, 256, 0, stream>>>(Wq, Wv, Wo, Wfc, Wpr, Wqvb, Wob, Wfcb, Wprb);

  // --- SSM branch
  ln_rows<<<4096, 256, 0, stream>>>(x, ln1w, hb);
  // [q|v] = h @ [Wq;Wv]^T
  gemm_nt<0, false><<<dim3(8, 128, 1), 256, 16384, stream>>>(
      hb, nullptr, Wqvb, nullptr, 512, 512, 512, 0, 0, 0,
      QV, 1024, nullptr, nullptr, 0.f, 0.f, nullptr, nullptr, nullptr, nullptr, nullptr);

  for (int d = 1; d < 4096; d <<= 1) {
    // YZ = q @ [P1;P2]^T  (q = QV cols 0..511, lda 1024)
    gemm_nt<0, false><<<dim3(8, 128, 1), 256, 16384, stream>>>(
        QV, nullptr, Xhi, nullptr, 512, 1024, 512, 0, 0, 0,
        YZ, 1024, nullptr, nullptr, 0.f, 0.f, nullptr, nullptr, nullptr, nullptr, nullptr);
    pscan_combine<<<4096 - d, 256, 0, stream>>>(YZ, QV, d);
  }

  qv_mul<<<4096, 256, 0, stream>>>(QV, hb);  // u -> hb
  // x2 = x + u @ Wo^T  -> d_out (fp32)
  gemm_nt<2, false><<<dim3(4, 128, 1), 256, 16384, stream>>>(
      hb, nullptr, Wob, nullptr, 512, 512, 512, 0, 0, 0,
      nullptr, 512, x, out, 0.f, 0.f, nullptr, nullptr, nullptr, nullptr, nullptr);

  // --- MLP branch
  ln_rows<<<4096, 256, 0, stream>>>(out, ln2w, hb);  // h2 -> hb
  gemm_nt<1, false><<<dim3(16, 128, 1), 256, 16384, stream>>>(
      hb, nullptr, Wfcb, nullptr, 512, 512, 512, 0, 0, 0,
      h3, 2048, nullptr, nullptr, 0.f, 0.f, nullptr, nullptr, nullptr, nullptr, nullptr);
  gemm_nt<2, false><<<dim3(4, 128, 1), 256, 16384, stream>>>(
      h3, nullptr, Wprb, nullptr, 2048, 2048, 2048, 0, 0, 0,
      nullptr, 512, out, out, 0.f, 0.f, nullptr, nullptr, nullptr, nullptr, nullptr);
}

// Round 4
// 1906.216 us; speedup vs baseline: 1.8546x; 1.6716x over previous
//
#include <hip/hip_runtime.h>
#include <hip/hip_bf16.h>

typedef __hip_bfloat16 bf16;
typedef __attribute__((ext_vector_type(8))) short short8;
typedef __attribute__((ext_vector_type(4))) short short4v;
typedef __attribute__((ext_vector_type(4))) float f32x4;

#define DEVINL static __device__ __forceinline__

DEVINL float b2f(bf16 x) { return __bfloat162float(x); }
DEVINL bf16 f2b(float x) { return __float2bfloat16(x); }
DEVINL float sb2f(short s) { return b2f(__builtin_bit_cast(bf16, s)); }
DEVINL short f2sb(float x) { return __builtin_bit_cast(short, f2b(x)); }

DEVINL void gload16(const void* g, void* l) {
  __builtin_amdgcn_global_load_lds(
      (const __attribute__((address_space(1))) void*)g,
      (__attribute__((address_space(3))) void*)l, 16, 0, 0);
}

DEVINL float wave_sum(float v) {
#pragma unroll
  for (int o = 32; o > 0; o >>= 1) v += __shfl_down(v, o, 64);
  return v;
}

DEVINL float wave_allsum(float v) {
#pragma unroll
  for (int o = 32; o > 0; o >>= 1) v += __shfl_xor(v, o, 64);
  return v;
}

// ---------------------------------------------------------------------------
// Generic NT GEMM: C[M,N] = sum_k A[m,k]*B[n,k]; A,B bf16 row-major.
// Tile: BM x BM (BM=128 or 64), BK=64, 256 threads = 4 waves in 2x2,
// per-wave (BM/2)^2 via (BM/32)^2 mfma_f32_16x16x32_bf16.
// MODE 0: store bf16 (LDS-coalesced)  MODE 1: exact-erf GELU bf16 (coalesced)
// MODE 2: outf = resf + acc (fp32)
// MODE 3: split-write hi/lo bf16 (NS gram)   MODE 4: NS update (see body)
// SPLIT: A/B hi+lo bf16 pairs; acc = Ah*Bh + Ah*Bl + Al*Bh (fp32-ish GEMM).
// Dynamic LDS = 32KB in all configs (staging; reused as C-tile in MODE 0/1).
// ---------------------------------------------------------------------------
template <int MODE, bool SPLIT, int BM>
__global__ __launch_bounds__(256) void gemm_nt(
    const bf16* __restrict__ A0, const bf16* __restrict__ A1,
    const bf16* __restrict__ B0, const bf16* __restrict__ B1,
    int K, int lda, int ldb, long bsA, long bsB, long bsC,
    bf16* __restrict__ outb, int ldo,
    const float* __restrict__ resf, float* __restrict__ outf,
    float alpha, float beta, float* __restrict__ Xf,
    bf16* __restrict__ Whi, bf16* __restrict__ Wlo,
    bf16* __restrict__ Thi, bf16* __restrict__ Tlo) {
  constexpr int BK = 64;
  constexpr int MT = BM / 32;           // mfma tiles per wave dim (4 or 2)
  constexpr int NLOAD = BM * BK / 2048; // 8-elem groups per thread per buffer
  extern __shared__ char smem[];
  bf16* AsH = (bf16*)smem;              // BM*BK elems
  bf16* BsH = AsH + BM * BK;
  bf16* AsL = BsH + BM * BK;            // SPLIT only
  bf16* BsL = AsL + BM * BK;

  const int t = threadIdx.x;
  const int lane = t & 63, w = t >> 6;
  const long bz = blockIdx.z;
  const bf16* Ab0 = A0 + bz * bsA;
  const bf16* Bb0 = B0 + bz * bsB;
  const bf16* Ab1 = SPLIT ? (A1 + bz * bsA) : nullptr;
  const bf16* Bb1 = SPLIT ? (B1 + bz * bsB) : nullptr;

  const int row0 = blockIdx.y * BM, col0 = blockIdx.x * BM;
  const int wm = (w >> 1) * (BM / 2), wn = (w & 1) * (BM / 2);
  const int jj = lane >> 4, r16 = lane & 15;

  f32x4 acc[MT][MT] = {};

  for (int k0 = 0; k0 < K; k0 += BK) {
    __syncthreads();
#pragma unroll
    for (int s = 0; s < NLOAD; ++s) {
      const int L = s * 256 + t;
      const int cj = L / BM, m = L % BM;
      const long ga = (long)(row0 + m) * lda + (k0 + cj * 8);
      const long gb = (long)(col0 + m) * ldb + (k0 + cj * 8);
      gload16(Ab0 + ga, AsH + L * 8);
      gload16(Bb0 + gb, BsH + L * 8);
      if (SPLIT) {
        gload16(Ab1 + ga, AsL + L * 8);
        gload16(Bb1 + gb, BsL + L * 8);
      }
    }
    __syncthreads();

#pragma unroll
    for (int kk = 0; kk < BK / 32; ++kk) {
      short8 a[MT], b[MT], al[MT], bl[MT];
#pragma unroll
      for (int mt = 0; mt < MT; ++mt) {
        const int o = (kk * 4 + jj) * BM * 8 + (wm + mt * 16 + r16) * 8;
        a[mt] = *(const short8*)(AsH + o);
        if (SPLIT) al[mt] = *(const short8*)(AsL + o);
      }
#pragma unroll
      for (int nt = 0; nt < MT; ++nt) {
        const int o = (kk * 4 + jj) * BM * 8 + (wn + nt * 16 + r16) * 8;
        b[nt] = *(const short8*)(BsH + o);
        if (SPLIT) bl[nt] = *(const short8*)(BsL + o);
      }
#pragma unroll
      for (int mt = 0; mt < MT; ++mt)
#pragma unroll
        for (int nt = 0; nt < MT; ++nt) {
          acc[mt][nt] = __builtin_amdgcn_mfma_f32_16x16x32_bf16(a[mt], b[nt], acc[mt][nt], 0, 0, 0);
          if (SPLIT) {
            acc[mt][nt] = __builtin_amdgcn_mfma_f32_16x16x32_bf16(a[mt], bl[nt], acc[mt][nt], 0, 0, 0);
            acc[mt][nt] = __builtin_amdgcn_mfma_f32_16x16x32_bf16(al[mt], b[nt], acc[mt][nt], 0, 0, 0);
          }
        }
    }
  }

  if (MODE == 0 || MODE == 1) {
    // Coalesced epilogue: acc -> LDS C-tile (bf16) -> 16B global stores.
    __syncthreads();
    bf16* Cs = (bf16*)smem;
#pragma unroll
    for (int mt = 0; mt < MT; ++mt)
#pragma unroll
      for (int nt = 0; nt < MT; ++nt)
#pragma unroll
        for (int r = 0; r < 4; ++r) {
          const int rl = wm + mt * 16 + jj * 4 + r;
          const int cl = wn + nt * 16 + r16;
          float v = acc[mt][nt][r];
          if (MODE == 1) v = 0.5f * v * (1.0f + erff(v * 0.70710678118654752f));
          Cs[rl * BM + cl] = f2b(v);
        }
    __syncthreads();
    constexpr int CPR = BM / 8;           // 16B chunks per row
    constexpr int RP = 256 / CPR;         // rows covered per pass
#pragma unroll
    for (int i = 0; i < BM * BM / 2048; ++i) {
      const int rl = t / CPR + i * RP;
      const int cl = (t % CPR) * 8;
      const short8 v8 = *(const short8*)(Cs + rl * BM + cl);
      *(short8*)(outb + bz * bsC + (long)(row0 + rl) * ldo + (col0 + cl)) = v8;
    }
    return;
  }

#pragma unroll
  for (int mt = 0; mt < MT; ++mt)
#pragma unroll
    for (int nt = 0; nt < MT; ++nt)
#pragma unroll
      for (int r = 0; r < 4; ++r) {
        const int row = row0 + wm + mt * 16 + jj * 4 + r;
        const int col = col0 + wn + nt * 16 + r16;
        const float v = acc[mt][nt][r];
        if (MODE == 2) {
          const long i = (long)row * ldo + col;
          outf[i] = resf[i] + v;
        } else if (MODE == 3) {
          const long i = bz * bsC + (long)row * 512 + col;
          const bf16 h = f2b(v);
          Whi[i] = h;
          Wlo[i] = f2b(v - b2f(h));
        } else if (MODE == 4) {
          const long i = bz * bsC + (long)row * 512 + col;
          const float nv = alpha * Xf[i] + beta * v;
          Xf[i] = nv;
          const bf16 h = f2b(nv);
          const bf16 l = f2b(nv - b2f(h));
          Whi[i] = h; Wlo[i] = l;
          const long it2 = bz * bsC + (long)col * 512 + row;
          Thi[it2] = h; Tlo[it2] = l;
        }
      }
}

// ---------------------------------------------------------------------------
// Frobenius norm^2 of W1, W2 (512x512 each). ||W||_F >= sigma_max -> safe.
// ---------------------------------------------------------------------------
__global__ __launch_bounds__(256) void fnorm(const float* __restrict__ W1,
                                             const float* __restrict__ W2,
                                             float* __restrict__ sigsq) {
  const int b = blockIdx.x >> 8;
  const float4 v = *(const float4*)((b ? W2 : W1) +
                                    (((long)(blockIdx.x & 255) * 256 + threadIdx.x) << 2));
  float s = v.x * v.x + v.y * v.y + v.z * v.z + v.w * v.w;
  s = wave_sum(s);
  if ((threadIdx.x & 63) == 0) atomicAdd(&sigsq[b], s);
}

// X0 = W / ||W||_F; emit fp32 master + hi/lo splits + transposed splits.
__global__ __launch_bounds__(256) void scale_init(
    const float* __restrict__ W1, const float* __restrict__ W2,
    const float* __restrict__ sigsq, float* __restrict__ Xf,
    bf16* __restrict__ Xhi, bf16* __restrict__ Xlo,
    bf16* __restrict__ Thi, bf16* __restrict__ Tlo) {
  const long idx = (long)blockIdx.x * 256 + threadIdx.x;  // 2*262144 total
  const int b = (int)(idx >> 18);
  const int i = (int)(idx & 262143);
  const float s = rsqrtf(sigsq[b]);
  const float val = (b ? W2[i] : W1[i]) * s;
  const long o = ((long)b << 18) + i;
  Xf[o] = val;
  const bf16 h = f2b(val);
  const bf16 l = f2b(val - b2f(h));
  Xhi[o] = h; Xlo[o] = l;
  const int r = i >> 9, c = i & 511;
  const long ot = ((long)b << 18) + (long)c * 512 + r;
  Thi[ot] = h; Tlo[ot] = l;
}

// All five weight matrices fp32 -> bf16 in one launch (4 elems/thread).
// Total elems: 3*262144 + 2*1048576 = 2,883,584 -> 2816 blocks of 1024 elems.
__global__ __launch_bounds__(256) void convert_weights(
    const float* __restrict__ Wq, const float* __restrict__ Wv,
    const float* __restrict__ Wo, const float* __restrict__ Wfc,
    const float* __restrict__ Wpr, bf16* __restrict__ Wqvb,
    bf16* __restrict__ Wob, bf16* __restrict__ Wfcb, bf16* __restrict__ Wprb) {
  const long e = ((long)blockIdx.x * 256 + threadIdx.x) << 2;
  const float* src; bf16* dst; long off;
  if (e < 262144)       { src = Wq;  dst = Wqvb;          off = e; }
  else if (e < 524288)  { src = Wv;  dst = Wqvb + 262144; off = e - 262144; }
  else if (e < 786432)  { src = Wo;  dst = Wob;           off = e - 524288; }
  else if (e < 1835008) { src = Wfc; dst = Wfcb;          off = e - 786432; }
  else                  { src = Wpr; dst = Wprb;          off = e - 1835008; }  // e < 2883584
  const float4 v = *(const float4*)(src + off);
  short4v o4;
  o4[0] = f2sb(v.x); o4[1] = f2sb(v.y); o4[2] = f2sb(v.z); o4[3] = f2sb(v.w);
  *(short4v*)(dst + off) = o4;
}

// LayerNorm over C=512, one wave per row (4 rows/block), bf16 out.
__global__ __launch_bounds__(256) void ln_rows(const float* __restrict__ x,
                                               const float* __restrict__ w,
                                               bf16* __restrict__ out) {
  const int row = (blockIdx.x << 2) + (threadIdx.x >> 6);
  const int lane = threadIdx.x & 63;
  const float* xr = x + (long)row * 512 + lane * 8;
  const float4 a = *(const float4*)xr;
  const float4 b = *(const float4*)(xr + 4);
  float v[8] = {a.x, a.y, a.z, a.w, b.x, b.y, b.z, b.w};
  float s1 = 0.f, s2 = 0.f;
#pragma unroll
  for (int i = 0; i < 8; ++i) { s1 += v[i]; s2 += v[i] * v[i]; }
  s1 = wave_allsum(s1);
  s2 = wave_allsum(s2);
  const float mean = s1 * (1.0f / 512.0f);
  const float var = s2 * (1.0f / 512.0f) - mean * mean;
  const float inv = rsqrtf(var + 1e-5f);
  const float4 w1 = *(const float4*)(w + lane * 8);
  const float4 w2 = *(const float4*)(w + lane * 8 + 4);
  const float wv[8] = {w1.x, w1.y, w1.z, w1.w, w2.x, w2.y, w2.z, w2.w};
  short8 o8;
#pragma unroll
  for (int i = 0; i < 8; ++i) o8[i] = f2sb((v[i] - mean) * inv * wv[i]);
  *(short8*)(out + (long)row * 512 + lane * 8) = o8;
}

// pscan combine: q[t] = rmsnorm(Y[t-d] + Z[t]) for t >= d; one wave per row.
// YZ is [16384][1024] bf16 (Y cols 0..511, Z cols 512..1023); q = QV cols 0..511.
__global__ __launch_bounds__(256) void pscan_combine(const bf16* __restrict__ YZ,
                                                     bf16* __restrict__ QV, int d) {
  const int span = 4096 - d;
  const int wid = (blockIdx.x << 2) + (threadIdx.x >> 6);  // grid = span blocks
  const int lane = threadIdx.x & 63;
  const int b = wid / span;
  const int tt = d + (wid - b * span);
  const long rowQ = (long)b * 4096 + tt;
  const short8 y8 = *(const short8*)(YZ + (rowQ - d) * 1024 + lane * 8);
  const short8 z8 = *(const short8*)(YZ + rowQ * 1024 + 512 + lane * 8);
  float s[8]; float ss = 0.f;
#pragma unroll
  for (int i = 0; i < 8; ++i) {
    const float v = sb2f(y8[i]) + sb2f(z8[i]);
    s[i] = v; ss += v * v;
  }
  ss = wave_allsum(ss);
  const float inv = rsqrtf(ss * (1.0f / 512.0f) + 1e-6f);
  short8 o8;
#pragma unroll
  for (int i = 0; i < 8; ++i) o8[i] = f2sb(s[i] * inv);
  *(short8*)(QV + rowQ * 1024 + lane * 8) = o8;
}

// u = q * v elementwise, 8 elems/thread.
__global__ __launch_bounds__(256) void qv_mul(const bf16* __restrict__ QV,
                                              bf16* __restrict__ u) {
  const long base = ((long)blockIdx.x * 256 + threadIdx.x) << 3;
  const long row = base >> 9;
  const int c = (int)(base & 511);
  const short8 q8 = *(const short8*)(QV + row * 1024 + c);
  const short8 v8 = *(const short8*)(QV + row * 1024 + 512 + c);
  short8 o8;
#pragma unroll
  for (int i = 0; i < 8; ++i) o8[i] = f2sb(sb2f(q8[i]) * sb2f(v8[i]));
  *(short8*)(u + row * 512 + c) = o8;
}

// ---------------------------------------------------------------------------
extern "C" void kernel_launch(void* const* d_in, const int* in_sizes, int n_in,
                              void* d_out, int out_size, void* d_ws, size_t ws_size,
                              hipStream_t stream) {
  (void)in_sizes; (void)n_in; (void)out_size; (void)ws_size;
  const float* x    = (const float*)d_in[0];
  const float* ln1w = (const float*)d_in[1];
  const float* Wq   = (const float*)d_in[2];
  const float* Wv   = (const float*)d_in[3];
  const float* Wo   = (const float*)d_in[4];
  // d_in[5] = identity: provably unused (positions t<d are never updated)
  const float* Wp1  = (const float*)d_in[6];
  const float* Wp2  = (const float*)d_in[7];
  const float* ln2w = (const float*)d_in[8];
  const float* Wfc  = (const float*)d_in[9];
  const float* Wpr  = (const float*)d_in[10];
  float* out = (float*)d_out;

  const long M = 16384;
  char* ws = (char*)d_ws;
  size_t off = 0;
  auto alloc = [&](size_t bytes) -> void* {
    void* p = ws + off;
    off += (bytes + 255) & ~(size_t)255;
    return p;
  };
  bf16* YZ   = (bf16*)alloc(M * 1024 * 2);   // 32MB; YZ+QV contiguous -> reused as h3 (64MB)
  bf16* QV   = (bf16*)alloc(M * 1024 * 2);   // 32MB
  bf16* hb   = (bf16*)alloc(M * 512 * 2);    // h -> u -> h2
  bf16* Wqvb = (bf16*)alloc(1024 * 512 * 2);
  bf16* Wob  = (bf16*)alloc(512 * 512 * 2);
  bf16* Wfcb = (bf16*)alloc(2048 * 512 * 2);
  bf16* Wprb = (bf16*)alloc(512 * 2048 * 2);
  float* Xf  = (float*)alloc(2 * 262144 * 4);
  bf16* Xhi  = (bf16*)alloc(2 * 262144 * 2);  // final P1;P2 bf16 (pscan B matrix)
  bf16* Xlo  = (bf16*)alloc(2 * 262144 * 2);
  bf16* XtAh = (bf16*)alloc(2 * 262144 * 2);
  bf16* XtAl = (bf16*)alloc(2 * 262144 * 2);
  bf16* XtBh = (bf16*)alloc(2 * 262144 * 2);
  bf16* XtBl = (bf16*)alloc(2 * 262144 * 2);
  bf16* Ghi  = (bf16*)alloc(2 * 262144 * 2);
  bf16* Glo  = (bf16*)alloc(2 * 262144 * 2);
  float* sig = (float*)alloc(256);
  bf16* h3 = YZ;  // [16384,2048] bf16 spans YZ+QV (both dead by then)

  const auto Z0 = nullptr;

  // --- polar decomposition of Wp1, Wp2 (batched Newton-Schulz, split-bf16 MFMA)
  hipMemsetAsync(sig, 0, 2 * sizeof(float), stream);
  fnorm<<<512, 256, 0, stream>>>(Wp1, Wp2, sig);
  scale_init<<<2048, 256, 0, stream>>>(Wp1, Wp2, sig, Xf, Xhi, Xlo, XtAh, XtAl);

  bf16 *tch = XtAh, *tcl = XtAl, *tnh = XtBh, *tnl = XtBl;
  const long S = 262144;
  for (int i = 0; i < 23; ++i) {
    const bool pol = (i >= 19);          // 19 doublings + 4 polish
    const float ac = pol ? 1.5f : 2.0f;
    const float bc = pol ? -0.5f : -1.0f;
    dim3 g(8, 8, 2);                     // 64-tiles: 128 blocks
    // G = X X^T
    gemm_nt<3, true, 64><<<g, 256, 32768, stream>>>(
        Xhi, Xlo, Xhi, Xlo, 512, 512, 512, S, S, S,
        Z0, 0, Z0, Z0, 0.f, 0.f, Z0, Ghi, Glo, Z0, Z0);
    // X = a*X + b*G*X   (B-operand = X^T splits)
    gemm_nt<4, true, 64><<<g, 256, 32768, stream>>>(
        Ghi, Glo, tch, tcl, 512, 512, 512, S, S, S,
        Z0, 0, Z0, Z0, ac, bc, Xf, Xhi, Xlo, tnh, tnl);
    bf16* sw;
    sw = tch; tch = tnh; tnh = sw;
    sw = tcl; tcl = tnl; tnl = sw;
  }

  // --- weight conversions to bf16 (one launch, 2816*1024 = 2,883,584 elems)
  convert_weights<<<2816, 256, 0, stream>>>(Wq, Wv, Wo, Wfc, Wpr, Wqvb, Wob, Wfcb, Wprb);

  // --- SSM branch
  ln_rows<<<4096, 256, 0, stream>>>(x, ln1w, hb);
  // [q|v] = h @ [Wq;Wv]^T
  gemm_nt<0, false, 128><<<dim3(8, 128, 1), 256, 32768, stream>>>(
      hb, Z0, Wqvb, Z0, 512, 512, 512, 0, 0, 0,
      QV, 1024, Z0, Z0, 0.f, 0.f, Z0, Z0, Z0, Z0, Z0);

  for (int d = 1; d < 4096; d <<= 1) {
    // YZ = q @ [P1;P2]^T  (q = QV cols 0..511, lda 1024)
    gemm_nt<0, false, 128><<<dim3(8, 128, 1), 256, 32768, stream>>>(
        QV, Z0, Xhi, Z0, 512, 1024, 512, 0, 0, 0,
        YZ, 1024, Z0, Z0, 0.f, 0.f, Z0, Z0, Z0, Z0, Z0);
    pscan_combine<<<4096 - d, 256, 0, stream>>>(YZ, QV, d);
  }

  qv_mul<<<4096, 256, 0, stream>>>(QV, hb);  // u -> hb
  // x2 = x + u @ Wo^T  -> d_out (fp32)
  gemm_nt<2, false, 128><<<dim3(4, 128, 1), 256, 32768, stream>>>(
      hb, Z0, Wob, Z0, 512, 512, 512, 0, 0, 0,
      Z0, 512, x, out, 0.f, 0.f, Z0, Z0, Z0, Z0, Z0);

  // --- MLP branch
  ln_rows<<<4096, 256, 0, stream>>>(out, ln2w, hb);  // h2 -> hb
  gemm_nt<1, false, 128><<<dim3(16, 128, 1), 256, 32768, stream>>>(
      hb, Z0, Wfcb, Z0, 512, 512, 512, 0, 0, 0,
      h3, 2048, Z0, Z0, 0.f, 0.f, Z0, Z0, Z0, Z0, Z0);
  gemm_nt<2, false, 128><<<dim3(4, 128, 1), 256, 32768, stream>>>(
      h3, Z0, Wprb, Z0, 2048, 2048, 2048, 0, 0, 0,
      Z0, 512, out, out, 0.f, 0.f, Z0, Z0, Z0, Z0, Z0);
}

// Round 5
// 1865.658 us; speedup vs baseline: 1.8949x; 1.0217x over previous
//
#include <hip/hip_runtime.h>
#include <hip/hip_bf16.h>

typedef __hip_bfloat16 bf16;
typedef __attribute__((ext_vector_type(8))) short short8;
typedef __attribute__((ext_vector_type(4))) short short4v;
typedef __attribute__((ext_vector_type(4))) float f32x4;

#define DEVINL static __device__ __forceinline__

DEVINL float b2f(bf16 x) { return __bfloat162float(x); }
DEVINL bf16 f2b(float x) { return __float2bfloat16(x); }
DEVINL float sb2f(short s) { return b2f(__builtin_bit_cast(bf16, s)); }
DEVINL short f2sb(float x) { return __builtin_bit_cast(short, f2b(x)); }

DEVINL void gload16(const void* g, void* l) {
  __builtin_amdgcn_global_load_lds(
      (const __attribute__((address_space(1))) void*)g,
      (__attribute__((address_space(3))) void*)l, 16, 0, 0);
}

DEVINL float wave_sum(float v) {
#pragma unroll
  for (int o = 32; o > 0; o >>= 1) v += __shfl_down(v, o, 64);
  return v;
}

DEVINL float wave_allsum(float v) {
#pragma unroll
  for (int o = 32; o > 0; o >>= 1) v += __shfl_xor(v, o, 64);
  return v;
}

// ---------------------------------------------------------------------------
// Generic NT GEMM: C[M,N] = sum_k A[m,k]*B[n,k]; A,B bf16 row-major.
// Tile: BM x BM, BK=64, 256 threads (4 waves 2x2).
// MODE 0: store bf16 (LDS-coalesced)  MODE 1: exact-erf GELU bf16 (coalesced)
// MODE 2: outf = resf + acc (fp32)
// MODE 3: split-write hi/lo bf16 (NS gram)   MODE 4: NS update
// SPLIT: A/B hi+lo bf16 pairs; acc = Ah*Bh + Ah*Bl + Al*Bh.
// ---------------------------------------------------------------------------
template <int MODE, bool SPLIT, int BM>
__global__ __launch_bounds__(256) void gemm_nt(
    const bf16* __restrict__ A0, const bf16* __restrict__ A1,
    const bf16* __restrict__ B0, const bf16* __restrict__ B1,
    int K, int lda, int ldb, long bsA, long bsB, long bsC,
    bf16* __restrict__ outb, int ldo,
    const float* __restrict__ resf, float* __restrict__ outf,
    float alpha, float beta, float* __restrict__ Xf,
    bf16* __restrict__ Whi, bf16* __restrict__ Wlo,
    bf16* __restrict__ Thi, bf16* __restrict__ Tlo) {
  constexpr int BK = 64;
  constexpr int MT = BM / 32;
  constexpr int NLOAD = BM * BK / 2048;
  extern __shared__ char smem[];
  bf16* AsH = (bf16*)smem;
  bf16* BsH = AsH + BM * BK;
  bf16* AsL = BsH + BM * BK;
  bf16* BsL = AsL + BM * BK;

  const int t = threadIdx.x;
  const int lane = t & 63, w = t >> 6;
  const long bz = blockIdx.z;
  const bf16* Ab0 = A0 + bz * bsA;
  const bf16* Bb0 = B0 + bz * bsB;
  const bf16* Ab1 = SPLIT ? (A1 + bz * bsA) : nullptr;
  const bf16* Bb1 = SPLIT ? (B1 + bz * bsB) : nullptr;

  const int row0 = blockIdx.y * BM, col0 = blockIdx.x * BM;
  const int wm = (w >> 1) * (BM / 2), wn = (w & 1) * (BM / 2);
  const int jj = lane >> 4, r16 = lane & 15;

  f32x4 acc[MT][MT] = {};

  for (int k0 = 0; k0 < K; k0 += BK) {
    __syncthreads();
#pragma unroll
    for (int s = 0; s < NLOAD; ++s) {
      const int L = s * 256 + t;
      const int cj = L / BM, m = L % BM;
      const long ga = (long)(row0 + m) * lda + (k0 + cj * 8);
      const long gb = (long)(col0 + m) * ldb + (k0 + cj * 8);
      gload16(Ab0 + ga, AsH + L * 8);
      gload16(Bb0 + gb, BsH + L * 8);
      if (SPLIT) {
        gload16(Ab1 + ga, AsL + L * 8);
        gload16(Bb1 + gb, BsL + L * 8);
      }
    }
    __syncthreads();

#pragma unroll
    for (int kk = 0; kk < BK / 32; ++kk) {
      short8 a[MT], b[MT], al[MT], bl[MT];
#pragma unroll
      for (int mt = 0; mt < MT; ++mt) {
        const int o = (kk * 4 + jj) * BM * 8 + (wm + mt * 16 + r16) * 8;
        a[mt] = *(const short8*)(AsH + o);
        if (SPLIT) al[mt] = *(const short8*)(AsL + o);
      }
#pragma unroll
      for (int nt = 0; nt < MT; ++nt) {
        const int o = (kk * 4 + jj) * BM * 8 + (wn + nt * 16 + r16) * 8;
        b[nt] = *(const short8*)(BsH + o);
        if (SPLIT) bl[nt] = *(const short8*)(BsL + o);
      }
#pragma unroll
      for (int mt = 0; mt < MT; ++mt)
#pragma unroll
        for (int nt = 0; nt < MT; ++nt) {
          acc[mt][nt] = __builtin_amdgcn_mfma_f32_16x16x32_bf16(a[mt], b[nt], acc[mt][nt], 0, 0, 0);
          if (SPLIT) {
            acc[mt][nt] = __builtin_amdgcn_mfma_f32_16x16x32_bf16(a[mt], bl[nt], acc[mt][nt], 0, 0, 0);
            acc[mt][nt] = __builtin_amdgcn_mfma_f32_16x16x32_bf16(al[mt], b[nt], acc[mt][nt], 0, 0, 0);
          }
        }
    }
  }

  if (MODE == 0 || MODE == 1) {
    __syncthreads();
    bf16* Cs = (bf16*)smem;
#pragma unroll
    for (int mt = 0; mt < MT; ++mt)
#pragma unroll
      for (int nt = 0; nt < MT; ++nt)
#pragma unroll
        for (int r = 0; r < 4; ++r) {
          const int rl = wm + mt * 16 + jj * 4 + r;
          const int cl = wn + nt * 16 + r16;
          float v = acc[mt][nt][r];
          if (MODE == 1) v = 0.5f * v * (1.0f + erff(v * 0.70710678118654752f));
          Cs[rl * BM + cl] = f2b(v);
        }
    __syncthreads();
    constexpr int CPR = BM / 8;
    constexpr int RP = 256 / CPR;
#pragma unroll
    for (int i = 0; i < BM * BM / 2048; ++i) {
      const int rl = t / CPR + i * RP;
      const int cl = (t % CPR) * 8;
      const short8 v8 = *(const short8*)(Cs + rl * BM + cl);
      *(short8*)(outb + bz * bsC + (long)(row0 + rl) * ldo + (col0 + cl)) = v8;
    }
    return;
  }

#pragma unroll
  for (int mt = 0; mt < MT; ++mt)
#pragma unroll
    for (int nt = 0; nt < MT; ++nt)
#pragma unroll
      for (int r = 0; r < 4; ++r) {
        const int row = row0 + wm + mt * 16 + jj * 4 + r;
        const int col = col0 + wn + nt * 16 + r16;
        const float v = acc[mt][nt][r];
        if (MODE == 2) {
          const long i = (long)row * ldo + col;
          outf[i] = resf[i] + v;
        } else if (MODE == 3) {
          const long i = bz * bsC + (long)row * 512 + col;
          const bf16 h = f2b(v);
          Whi[i] = h;
          Wlo[i] = f2b(v - b2f(h));
        } else if (MODE == 4) {
          const long i = bz * bsC + (long)row * 512 + col;
          const float nv = alpha * Xf[i] + beta * v;
          Xf[i] = nv;
          const bf16 h = f2b(nv);
          const bf16 l = f2b(nv - b2f(h));
          Whi[i] = h; Wlo[i] = l;
          const long it2 = bz * bsC + (long)col * 512 + row;
          Thi[it2] = h; Tlo[it2] = l;
        }
      }
}

// ---------------------------------------------------------------------------
// Fused pscan level GEMM: S[t,c] = sum_k q[clamp(t-d),k]*P1[c,k]
//                                 + sum_k q[t,k]*P2[c,k]   (K=1024 concat)
// q = QV cols 0..511 (lda 1024). Pcat = [c][P1[c,:] | P2[c,:]] (512x1024).
// Tile 128x128, BK=64, 16 K-iters. Rows t<d produce garbage (clamped read),
// ignored by combine. Row-trimmed grid: rows [start, 4096) per batch.
// ---------------------------------------------------------------------------
__global__ __launch_bounds__(256) void pscan_gemm(
    const bf16* __restrict__ QV, const bf16* __restrict__ Pcat,
    bf16* __restrict__ S, int d, int start, int nyb) {
  constexpr int BM = 128, BK = 64;
  extern __shared__ char smem[];  // 32 KB
  bf16* As = (bf16*)smem;
  bf16* Bs = As + BM * BK;
  const int t = threadIdx.x;
  const int lane = t & 63, w = t >> 6;
  const int b = blockIdx.y / nyb;
  const int ty = blockIdx.y - b * nyb;
  const int batch0 = b * 4096;
  const int row0 = batch0 + start + ty * 128;
  const int col0 = blockIdx.x * 128;
  const int wm = (w >> 1) * 64, wn = (w & 1) * 64;
  const int jj = lane >> 4, r16 = lane & 15;

  f32x4 acc[4][4] = {};

  for (int k0 = 0; k0 < 1024; k0 += BK) {
    __syncthreads();
#pragma unroll
    for (int s = 0; s < 4; ++s) {
      const int L = s * 256 + t;
      const int cj = L >> 7, m = L & 127;
      const int k = k0 + cj * 8;
      long ga;
      if (k0 < 512) {                       // uniform per iter (64 | 512)
        int rs = row0 + m - d;
        if (rs < batch0) rs = batch0;       // clamped: garbage row, discarded
        ga = (long)rs * 1024 + k;
      } else {
        ga = (long)(row0 + m) * 1024 + (k - 512);
      }
      gload16(QV + ga, As + L * 8);
      gload16(Pcat + (long)(col0 + m) * 1024 + k, Bs + L * 8);
    }
    __syncthreads();
#pragma unroll
    for (int kk = 0; kk < 2; ++kk) {
      short8 a[4], bb[4];
#pragma unroll
      for (int mt = 0; mt < 4; ++mt)
        a[mt] = *(const short8*)(As + (kk * 4 + jj) * 1024 + (wm + mt * 16 + r16) * 8);
#pragma unroll
      for (int nt = 0; nt < 4; ++nt)
        bb[nt] = *(const short8*)(Bs + (kk * 4 + jj) * 1024 + (wn + nt * 16 + r16) * 8);
#pragma unroll
      for (int mt = 0; mt < 4; ++mt)
#pragma unroll
        for (int nt = 0; nt < 4; ++nt)
          acc[mt][nt] = __builtin_amdgcn_mfma_f32_16x16x32_bf16(a[mt], bb[nt], acc[mt][nt], 0, 0, 0);
    }
  }

  // Coalesced epilogue: acc -> LDS bf16 C-tile -> 16B stores (ldo = 512).
  __syncthreads();
  bf16* Cs = (bf16*)smem;
#pragma unroll
  for (int mt = 0; mt < 4; ++mt)
#pragma unroll
    for (int nt = 0; nt < 4; ++nt)
#pragma unroll
      for (int r = 0; r < 4; ++r) {
        const int rl = wm + mt * 16 + jj * 4 + r;
        const int cl = wn + nt * 16 + r16;
        Cs[rl * 128 + cl] = f2b(acc[mt][nt][r]);
      }
  __syncthreads();
#pragma unroll
  for (int i = 0; i < 8; ++i) {
    const int rl = t / 16 + i * 16;
    const int cl = (t % 16) * 8;
    const short8 v8 = *(const short8*)(Cs + rl * 128 + cl);
    *(short8*)(S + (long)(row0 + rl) * 512 + (col0 + cl)) = v8;
  }
}

// Pcat[c][k] = k<512 ? P1[c][k] : P2[c][k-512]; P1=Xhi[0..], P2=Xhi[262144..].
__global__ __launch_bounds__(256) void repack_pcat(const bf16* __restrict__ Xhi,
                                                   bf16* __restrict__ Pcat) {
  const int e = (blockIdx.x * 256 + threadIdx.x) << 3;  // 524288 elems, 256 blocks
  const int c = e >> 10, k = e & 1023;
  const bf16* src = (k < 512) ? (Xhi + (long)c * 512 + k)
                              : (Xhi + 262144 + (long)c * 512 + (k - 512));
  *(short8*)(Pcat + e) = *(const short8*)src;
}

// ---------------------------------------------------------------------------
// Frobenius norm^2 of W1, W2 (512x512 each). ||W||_F >= sigma_max -> safe.
// ---------------------------------------------------------------------------
__global__ __launch_bounds__(256) void fnorm(const float* __restrict__ W1,
                                             const float* __restrict__ W2,
                                             float* __restrict__ sigsq) {
  const int b = blockIdx.x >> 8;
  const float4 v = *(const float4*)((b ? W2 : W1) +
                                    (((long)(blockIdx.x & 255) * 256 + threadIdx.x) << 2));
  float s = v.x * v.x + v.y * v.y + v.z * v.z + v.w * v.w;
  s = wave_sum(s);
  if ((threadIdx.x & 63) == 0) atomicAdd(&sigsq[b], s);
}

// X0 = W / ||W||_F; emit fp32 master + hi/lo splits + transposed splits.
__global__ __launch_bounds__(256) void scale_init(
    const float* __restrict__ W1, const float* __restrict__ W2,
    const float* __restrict__ sigsq, float* __restrict__ Xf,
    bf16* __restrict__ Xhi, bf16* __restrict__ Xlo,
    bf16* __restrict__ Thi, bf16* __restrict__ Tlo) {
  const long idx = (long)blockIdx.x * 256 + threadIdx.x;  // 2*262144 total
  const int b = (int)(idx >> 18);
  const int i = (int)(idx & 262143);
  const float s = rsqrtf(sigsq[b]);
  const float val = (b ? W2[i] : W1[i]) * s;
  const long o = ((long)b << 18) + i;
  Xf[o] = val;
  const bf16 h = f2b(val);
  const bf16 l = f2b(val - b2f(h));
  Xhi[o] = h; Xlo[o] = l;
  const int r = i >> 9, c = i & 511;
  const long ot = ((long)b << 18) + (long)c * 512 + r;
  Thi[ot] = h; Tlo[ot] = l;
}

// All five weight matrices fp32 -> bf16 in one launch (4 elems/thread).
// Total: 3*262144 + 2*1048576 = 2,883,584 elems -> 2816 blocks.
__global__ __launch_bounds__(256) void convert_weights(
    const float* __restrict__ Wq, const float* __restrict__ Wv,
    const float* __restrict__ Wo, const float* __restrict__ Wfc,
    const float* __restrict__ Wpr, bf16* __restrict__ Wqvb,
    bf16* __restrict__ Wob, bf16* __restrict__ Wfcb, bf16* __restrict__ Wprb) {
  const long e = ((long)blockIdx.x * 256 + threadIdx.x) << 2;
  const float* src; bf16* dst; long off;
  if (e < 262144)       { src = Wq;  dst = Wqvb;          off = e; }
  else if (e < 524288)  { src = Wv;  dst = Wqvb + 262144; off = e - 262144; }
  else if (e < 786432)  { src = Wo;  dst = Wob;           off = e - 524288; }
  else if (e < 1835008) { src = Wfc; dst = Wfcb;          off = e - 786432; }
  else                  { src = Wpr; dst = Wprb;          off = e - 1835008; }
  const float4 v = *(const float4*)(src + off);
  short4v o4;
  o4[0] = f2sb(v.x); o4[1] = f2sb(v.y); o4[2] = f2sb(v.z); o4[3] = f2sb(v.w);
  *(short4v*)(dst + off) = o4;
}

// LayerNorm over C=512, one wave per row (4 rows/block), bf16 out.
__global__ __launch_bounds__(256) void ln_rows(const float* __restrict__ x,
                                               const float* __restrict__ w,
                                               bf16* __restrict__ out) {
  const int row = (blockIdx.x << 2) + (threadIdx.x >> 6);
  const int lane = threadIdx.x & 63;
  const float* xr = x + (long)row * 512 + lane * 8;
  const float4 a = *(const float4*)xr;
  const float4 b = *(const float4*)(xr + 4);
  float v[8] = {a.x, a.y, a.z, a.w, b.x, b.y, b.z, b.w};
  float s1 = 0.f, s2 = 0.f;
#pragma unroll
  for (int i = 0; i < 8; ++i) { s1 += v[i]; s2 += v[i] * v[i]; }
  s1 = wave_allsum(s1);
  s2 = wave_allsum(s2);
  const float mean = s1 * (1.0f / 512.0f);
  const float var = s2 * (1.0f / 512.0f) - mean * mean;
  const float inv = rsqrtf(var + 1e-5f);
  const float4 w1 = *(const float4*)(w + lane * 8);
  const float4 w2 = *(const float4*)(w + lane * 8 + 4);
  const float wv[8] = {w1.x, w1.y, w1.z, w1.w, w2.x, w2.y, w2.z, w2.w};
  short8 o8;
#pragma unroll
  for (int i = 0; i < 8; ++i) o8[i] = f2sb((v[i] - mean) * inv * wv[i]);
  *(short8*)(out + (long)row * 512 + lane * 8) = o8;
}

// pscan combine: q[t] = rmsnorm(S[t]) for t >= d; one wave per row.
// S is [16384][512] bf16; q = QV cols 0..511 (stride 1024).
__global__ __launch_bounds__(256) void pscan_combine(const bf16* __restrict__ S,
                                                     bf16* __restrict__ QV, int d) {
  const int span = 4096 - d;
  const int wid = (blockIdx.x << 2) + (threadIdx.x >> 6);  // grid = span blocks
  const int lane = threadIdx.x & 63;
  const int b = wid / span;
  const int tt = d + (wid - b * span);
  const long rowQ = (long)b * 4096 + tt;
  const short8 s8 = *(const short8*)(S + rowQ * 512 + lane * 8);
  float s[8]; float ss = 0.f;
#pragma unroll
  for (int i = 0; i < 8; ++i) {
    const float v = sb2f(s8[i]);
    s[i] = v; ss += v * v;
  }
  ss = wave_allsum(ss);
  const float inv = rsqrtf(ss * (1.0f / 512.0f) + 1e-6f);
  short8 o8;
#pragma unroll
  for (int i = 0; i < 8; ++i) o8[i] = f2sb(s[i] * inv);
  *(short8*)(QV + rowQ * 1024 + lane * 8) = o8;
}

// u = q * v elementwise, 8 elems/thread.
__global__ __launch_bounds__(256) void qv_mul(const bf16* __restrict__ QV,
                                              bf16* __restrict__ u) {
  const long base = ((long)blockIdx.x * 256 + threadIdx.x) << 3;
  const long row = base >> 9;
  const int c = (int)(base & 511);
  const short8 q8 = *(const short8*)(QV + row * 1024 + c);
  const short8 v8 = *(const short8*)(QV + row * 1024 + 512 + c);
  short8 o8;
#pragma unroll
  for (int i = 0; i < 8; ++i) o8[i] = f2sb(sb2f(q8[i]) * sb2f(v8[i]));
  *(short8*)(u + row * 512 + c) = o8;
}

// ---------------------------------------------------------------------------
extern "C" void kernel_launch(void* const* d_in, const int* in_sizes, int n_in,
                              void* d_out, int out_size, void* d_ws, size_t ws_size,
                              hipStream_t stream) {
  (void)in_sizes; (void)n_in; (void)out_size; (void)ws_size;
  const float* x    = (const float*)d_in[0];
  const float* ln1w = (const float*)d_in[1];
  const float* Wq   = (const float*)d_in[2];
  const float* Wv   = (const float*)d_in[3];
  const float* Wo   = (const float*)d_in[4];
  // d_in[5] = identity: provably unused (positions t<d are never updated)
  const float* Wp1  = (const float*)d_in[6];
  const float* Wp2  = (const float*)d_in[7];
  const float* ln2w = (const float*)d_in[8];
  const float* Wfc  = (const float*)d_in[9];
  const float* Wpr  = (const float*)d_in[10];
  float* out = (float*)d_out;

  const long M = 16384;
  char* ws = (char*)d_ws;
  size_t off = 0;
  auto alloc = [&](size_t bytes) -> void* {
    void* p = ws + off;
    off += (bytes + 255) & ~(size_t)255;
    return p;
  };
  bf16* YZ   = (bf16*)alloc(M * 1024 * 2);   // S uses first 16MB; +QV = h3 (64MB)
  bf16* QV   = (bf16*)alloc(M * 1024 * 2);   // 32MB
  bf16* hb   = (bf16*)alloc(M * 512 * 2);    // h -> u -> h2
  bf16* Wqvb = (bf16*)alloc(1024 * 512 * 2);
  bf16* Wob  = (bf16*)alloc(512 * 512 * 2);
  bf16* Wfcb = (bf16*)alloc(2048 * 512 * 2);
  bf16* Wprb = (bf16*)alloc(512 * 2048 * 2);
  float* Xf  = (float*)alloc(2 * 262144 * 4);
  bf16* Xhi  = (bf16*)alloc(2 * 262144 * 2);  // final P1;P2 bf16
  bf16* Xlo  = (bf16*)alloc(2 * 262144 * 2);
  bf16* XtAh = (bf16*)alloc(2 * 262144 * 2);
  bf16* XtAl = (bf16*)alloc(2 * 262144 * 2);
  bf16* XtBh = (bf16*)alloc(2 * 262144 * 2);
  bf16* XtBl = (bf16*)alloc(2 * 262144 * 2);
  bf16* Ghi  = (bf16*)alloc(2 * 262144 * 2);
  bf16* Glo  = (bf16*)alloc(2 * 262144 * 2);
  bf16* Pcat = (bf16*)alloc(512 * 1024 * 2);  // [c][P1[c,:]|P2[c,:]]
  float* sig = (float*)alloc(256);
  bf16* S  = YZ;   // [16384][512] bf16, 16MB
  bf16* h3 = YZ;   // [16384,2048] bf16 spans YZ+QV (both dead by then)

  const auto Z0 = nullptr;

  // --- polar decomposition of Wp1, Wp2 (batched Newton-Schulz, split-bf16 MFMA)
  hipMemsetAsync(sig, 0, 2 * sizeof(float), stream);
  fnorm<<<512, 256, 0, stream>>>(Wp1, Wp2, sig);
  scale_init<<<2048, 256, 0, stream>>>(Wp1, Wp2, sig, Xf, Xhi, Xlo, XtAh, XtAl);

  bf16 *tch = XtAh, *tcl = XtAl, *tnh = XtBh, *tnl = XtBl;
  const long Sz = 262144;
  for (int i = 0; i < 23; ++i) {
    const bool pol = (i >= 19);          // 19 doublings + 4 polish
    const float ac = pol ? 1.5f : 2.0f;
    const float bc = pol ? -0.5f : -1.0f;
    dim3 g(8, 8, 2);
    gemm_nt<3, true, 64><<<g, 256, 32768, stream>>>(
        Xhi, Xlo, Xhi, Xlo, 512, 512, 512, Sz, Sz, Sz,
        Z0, 0, Z0, Z0, 0.f, 0.f, Z0, Ghi, Glo, Z0, Z0);
    gemm_nt<4, true, 64><<<g, 256, 32768, stream>>>(
        Ghi, Glo, tch, tcl, 512, 512, 512, Sz, Sz, Sz,
        Z0, 0, Z0, Z0, ac, bc, Xf, Xhi, Xlo, tnh, tnl);
    bf16* sw;
    sw = tch; tch = tnh; tnh = sw;
    sw = tcl; tcl = tnl; tnl = sw;
  }
  repack_pcat<<<256, 256, 0, stream>>>(Xhi, Pcat);

  // --- weight conversions to bf16 (one launch)
  convert_weights<<<2816, 256, 0, stream>>>(Wq, Wv, Wo, Wfc, Wpr, Wqvb, Wob, Wfcb, Wprb);

  // --- SSM branch
  ln_rows<<<4096, 256, 0, stream>>>(x, ln1w, hb);
  // [q|v] = h @ [Wq;Wv]^T
  gemm_nt<0, false, 128><<<dim3(8, 128, 1), 256, 32768, stream>>>(
      hb, Z0, Wqvb, Z0, 512, 512, 512, 0, 0, 0,
      QV, 1024, Z0, Z0, 0.f, 0.f, Z0, Z0, Z0, Z0, Z0);

  for (int d = 1; d < 4096; d <<= 1) {
    // S = [q[t-d]|q[t]] @ Pcat^T  (K=1024), rows [d&~127, 4096) per batch
    const int start = d & ~127;
    const int nyb = (4096 - start) >> 7;
    pscan_gemm<<<dim3(4, 4 * nyb, 1), 256, 32768, stream>>>(QV, Pcat, S, d, start, nyb);
    pscan_combine<<<4096 - d, 256, 0, stream>>>(S, QV, d);
  }

  qv_mul<<<4096, 256, 0, stream>>>(QV, hb);  // u -> hb
  // x2 = x + u @ Wo^T  -> d_out (fp32)
  gemm_nt<2, false, 128><<<dim3(4, 128, 1), 256, 32768, stream>>>(
      hb, Z0, Wob, Z0, 512, 512, 512, 0, 0, 0,
      Z0, 512, x, out, 0.f, 0.f, Z0, Z0, Z0, Z0, Z0);

  // --- MLP branch
  ln_rows<<<4096, 256, 0, stream>>>(out, ln2w, hb);  // h2 -> hb
  gemm_nt<1, false, 128><<<dim3(16, 128, 1), 256, 32768, stream>>>(
      hb, Z0, Wfcb, Z0, 512, 512, 512, 0, 0, 0,
      h3, 2048, Z0, Z0, 0.f, 0.f, Z0, Z0, Z0, Z0, Z0);
  gemm_nt<2, false, 128><<<dim3(4, 128, 1), 256, 32768, stream>>>(
      h3, Z0, Wprb, Z0, 2048, 2048, 2048, 0, 0, 0,
      Z0, 512, out, out, 0.f, 0.f, Z0, Z0, Z0, Z0, Z0);
}

// Round 6
// 1655.336 us; speedup vs baseline: 2.1357x; 1.1271x over previous
//
#include <hip/hip_runtime.h>
#include <hip/hip_bf16.h>

typedef __hip_bfloat16 bf16;
typedef __attribute__((ext_vector_type(8))) short short8;
typedef __attribute__((ext_vector_type(4))) short short4v;
typedef __attribute__((ext_vector_type(4))) float f32x4;

#define DEVINL static __device__ __forceinline__

DEVINL float b2f(bf16 x) { return __bfloat162float(x); }
DEVINL bf16 f2b(float x) { return __float2bfloat16(x); }
DEVINL float sb2f(short s) { return b2f(__builtin_bit_cast(bf16, s)); }
DEVINL short f2sb(float x) { return __builtin_bit_cast(short, f2b(x)); }

DEVINL void gload16(const void* g, void* l) {
  __builtin_amdgcn_global_load_lds(
      (const __attribute__((address_space(1))) void*)g,
      (__attribute__((address_space(3))) void*)l, 16, 0, 0);
}

DEVINL float wave_sum(float v) {
#pragma unroll
  for (int o = 32; o > 0; o >>= 1) v += __shfl_down(v, o, 64);
  return v;
}

DEVINL float wave_allsum(float v) {
#pragma unroll
  for (int o = 32; o > 0; o >>= 1) v += __shfl_xor(v, o, 64);
  return v;
}

// ---------------------------------------------------------------------------
// Generic NT GEMM: C[M,N] = sum_k A[m,k]*B[n,k]; A,B bf16 row-major.
// GRID: blockIdx.x = ROW tile (fast dim -> consecutive blocks have unique A
// stripes, spread across XCDs; shared B is tiny and L2-cached per XCD).
// Tile: BM x BM, BK=64, 256 threads (4 waves 2x2).
// MODE 0: store bf16 (LDS-coalesced)  MODE 1: exact-erf GELU bf16 (coalesced)
// MODE 2: outf = resf + acc (fp32)
// MODE 3: split-write hi/lo bf16 (NS gram)   MODE 4: NS update
// SPLIT: A/B hi+lo bf16 pairs; acc = Ah*Bh + Ah*Bl + Al*Bh.
// ---------------------------------------------------------------------------
template <int MODE, bool SPLIT, int BM>
__global__ __launch_bounds__(256) void gemm_nt(
    const bf16* __restrict__ A0, const bf16* __restrict__ A1,
    const bf16* __restrict__ B0, const bf16* __restrict__ B1,
    int K, int lda, int ldb, long bsA, long bsB, long bsC,
    bf16* __restrict__ outb, int ldo,
    const float* __restrict__ resf, float* __restrict__ outf,
    float alpha, float beta, float* __restrict__ Xf,
    bf16* __restrict__ Whi, bf16* __restrict__ Wlo,
    bf16* __restrict__ Thi, bf16* __restrict__ Tlo) {
  constexpr int BK = 64;
  constexpr int MT = BM / 32;
  constexpr int NLOAD = BM * BK / 2048;
  extern __shared__ char smem[];
  bf16* AsH = (bf16*)smem;
  bf16* BsH = AsH + BM * BK;
  bf16* AsL = BsH + BM * BK;
  bf16* BsL = AsL + BM * BK;

  const int t = threadIdx.x;
  const int lane = t & 63, w = t >> 6;
  const long bz = blockIdx.z;
  const bf16* Ab0 = A0 + bz * bsA;
  const bf16* Bb0 = B0 + bz * bsB;
  const bf16* Ab1 = SPLIT ? (A1 + bz * bsA) : nullptr;
  const bf16* Bb1 = SPLIT ? (B1 + bz * bsB) : nullptr;

  const int row0 = blockIdx.x * BM, col0 = blockIdx.y * BM;  // x = row (fast)
  const int wm = (w >> 1) * (BM / 2), wn = (w & 1) * (BM / 2);
  const int jj = lane >> 4, r16 = lane & 15;

  f32x4 acc[MT][MT] = {};

  for (int k0 = 0; k0 < K; k0 += BK) {
    __syncthreads();
#pragma unroll
    for (int s = 0; s < NLOAD; ++s) {
      const int L = s * 256 + t;
      const int cj = L / BM, m = L % BM;
      const long ga = (long)(row0 + m) * lda + (k0 + cj * 8);
      const long gb = (long)(col0 + m) * ldb + (k0 + cj * 8);
      gload16(Ab0 + ga, AsH + L * 8);
      gload16(Bb0 + gb, BsH + L * 8);
      if (SPLIT) {
        gload16(Ab1 + ga, AsL + L * 8);
        gload16(Bb1 + gb, BsL + L * 8);
      }
    }
    __syncthreads();

#pragma unroll
    for (int kk = 0; kk < BK / 32; ++kk) {
      short8 a[MT], b[MT], al[MT], bl[MT];
#pragma unroll
      for (int mt = 0; mt < MT; ++mt) {
        const int o = (kk * 4 + jj) * BM * 8 + (wm + mt * 16 + r16) * 8;
        a[mt] = *(const short8*)(AsH + o);
        if (SPLIT) al[mt] = *(const short8*)(AsL + o);
      }
#pragma unroll
      for (int nt = 0; nt < MT; ++nt) {
        const int o = (kk * 4 + jj) * BM * 8 + (wn + nt * 16 + r16) * 8;
        b[nt] = *(const short8*)(BsH + o);
        if (SPLIT) bl[nt] = *(const short8*)(BsL + o);
      }
#pragma unroll
      for (int mt = 0; mt < MT; ++mt)
#pragma unroll
        for (int nt = 0; nt < MT; ++nt) {
          acc[mt][nt] = __builtin_amdgcn_mfma_f32_16x16x32_bf16(a[mt], b[nt], acc[mt][nt], 0, 0, 0);
          if (SPLIT) {
            acc[mt][nt] = __builtin_amdgcn_mfma_f32_16x16x32_bf16(a[mt], bl[nt], acc[mt][nt], 0, 0, 0);
            acc[mt][nt] = __builtin_amdgcn_mfma_f32_16x16x32_bf16(al[mt], b[nt], acc[mt][nt], 0, 0, 0);
          }
        }
    }
  }

  if (MODE == 0 || MODE == 1) {
    __syncthreads();
    bf16* Cs = (bf16*)smem;
#pragma unroll
    for (int mt = 0; mt < MT; ++mt)
#pragma unroll
      for (int nt = 0; nt < MT; ++nt)
#pragma unroll
        for (int r = 0; r < 4; ++r) {
          const int rl = wm + mt * 16 + jj * 4 + r;
          const int cl = wn + nt * 16 + r16;
          float v = acc[mt][nt][r];
          if (MODE == 1) v = 0.5f * v * (1.0f + erff(v * 0.70710678118654752f));
          Cs[rl * BM + cl] = f2b(v);
        }
    __syncthreads();
    constexpr int CPR = BM / 8;
    constexpr int RP = 256 / CPR;
#pragma unroll
    for (int i = 0; i < BM * BM / 2048; ++i) {
      const int rl = t / CPR + i * RP;
      const int cl = (t % CPR) * 8;
      const short8 v8 = *(const short8*)(Cs + rl * BM + cl);
      *(short8*)(outb + bz * bsC + (long)(row0 + rl) * ldo + (col0 + cl)) = v8;
    }
    return;
  }

#pragma unroll
  for (int mt = 0; mt < MT; ++mt)
#pragma unroll
    for (int nt = 0; nt < MT; ++nt)
#pragma unroll
      for (int r = 0; r < 4; ++r) {
        const int row = row0 + wm + mt * 16 + jj * 4 + r;
        const int col = col0 + wn + nt * 16 + r16;
        const float v = acc[mt][nt][r];
        if (MODE == 2) {
          const long i = (long)row * ldo + col;
          outf[i] = resf[i] + v;
        } else if (MODE == 3) {
          const long i = bz * bsC + (long)row * 512 + col;
          const bf16 h = f2b(v);
          Whi[i] = h;
          Wlo[i] = f2b(v - b2f(h));
        } else if (MODE == 4) {
          const long i = bz * bsC + (long)row * 512 + col;
          const float nv = alpha * Xf[i] + beta * v;
          Xf[i] = nv;
          const bf16 h = f2b(nv);
          const bf16 l = f2b(nv - b2f(h));
          Whi[i] = h; Wlo[i] = l;
          const long it2 = bz * bsC + (long)col * 512 + row;
          Thi[it2] = h; Tlo[it2] = l;
        }
      }
}

// ---------------------------------------------------------------------------
// Fused pscan level GEMM: S[t,c] = sum_k q[clamp(t-d),k]*P1[c,k]
//                                 + sum_k q[t,k]*P2[c,k]   (K=1024 concat)
// q = QV cols 0..511 (lda 1024). Pcat = [c][P1[c,:] | P2[c,:]] (512x1024).
// GRID: x = row tile (4*nyb, fast -> unique A per consecutive block),
//       y = col tile (4). Rows t<d: clamped garbage, ignored by combine.
// ---------------------------------------------------------------------------
__global__ __launch_bounds__(256) void pscan_gemm(
    const bf16* __restrict__ QV, const bf16* __restrict__ Pcat,
    bf16* __restrict__ S, int d, int start, int nyb) {
  constexpr int BM = 128, BK = 64;
  extern __shared__ char smem[];  // 32 KB
  bf16* As = (bf16*)smem;
  bf16* Bs = As + BM * BK;
  const int t = threadIdx.x;
  const int lane = t & 63, w = t >> 6;
  const int b = blockIdx.x / nyb;
  const int ty = blockIdx.x - b * nyb;
  const int batch0 = b * 4096;
  const int row0 = batch0 + start + ty * 128;
  const int col0 = blockIdx.y * 128;
  const int wm = (w >> 1) * 64, wn = (w & 1) * 64;
  const int jj = lane >> 4, r16 = lane & 15;

  f32x4 acc[4][4] = {};

  for (int k0 = 0; k0 < 1024; k0 += BK) {
    __syncthreads();
#pragma unroll
    for (int s = 0; s < 4; ++s) {
      const int L = s * 256 + t;
      const int cj = L >> 7, m = L & 127;
      const int k = k0 + cj * 8;
      long ga;
      if (k0 < 512) {                       // uniform per iter
        int rs = row0 + m - d;
        if (rs < batch0) rs = batch0;       // clamped: garbage row, discarded
        ga = (long)rs * 1024 + k;
      } else {
        ga = (long)(row0 + m) * 1024 + (k - 512);
      }
      gload16(QV + ga, As + L * 8);
      gload16(Pcat + (long)(col0 + m) * 1024 + k, Bs + L * 8);
    }
    __syncthreads();
#pragma unroll
    for (int kk = 0; kk < 2; ++kk) {
      short8 a[4], bb[4];
#pragma unroll
      for (int mt = 0; mt < 4; ++mt)
        a[mt] = *(const short8*)(As + (kk * 4 + jj) * 1024 + (wm + mt * 16 + r16) * 8);
#pragma unroll
      for (int nt = 0; nt < 4; ++nt)
        bb[nt] = *(const short8*)(Bs + (kk * 4 + jj) * 1024 + (wn + nt * 16 + r16) * 8);
#pragma unroll
      for (int mt = 0; mt < 4; ++mt)
#pragma unroll
        for (int nt = 0; nt < 4; ++nt)
          acc[mt][nt] = __builtin_amdgcn_mfma_f32_16x16x32_bf16(a[mt], bb[nt], acc[mt][nt], 0, 0, 0);
    }
  }

  // Coalesced epilogue: acc -> LDS bf16 C-tile -> 16B stores (ldo = 512).
  __syncthreads();
  bf16* Cs = (bf16*)smem;
#pragma unroll
  for (int mt = 0; mt < 4; ++mt)
#pragma unroll
    for (int nt = 0; nt < 4; ++nt)
#pragma unroll
      for (int r = 0; r < 4; ++r) {
        const int rl = wm + mt * 16 + jj * 4 + r;
        const int cl = wn + nt * 16 + r16;
        Cs[rl * 128 + cl] = f2b(acc[mt][nt][r]);
      }
  __syncthreads();
#pragma unroll
  for (int i = 0; i < 8; ++i) {
    const int rl = t / 16 + i * 16;
    const int cl = (t % 16) * 8;
    const short8 v8 = *(const short8*)(Cs + rl * 128 + cl);
    *(short8*)(S + (long)(row0 + rl) * 512 + (col0 + cl)) = v8;
  }
}

// Pcat[c][k] = k<512 ? P1[c][k] : P2[c][k-512]; P1=Xhi[0..], P2=Xhi[262144..].
__global__ __launch_bounds__(256) void repack_pcat(const bf16* __restrict__ Xhi,
                                                   bf16* __restrict__ Pcat) {
  const int e = (blockIdx.x * 256 + threadIdx.x) << 3;  // 524288 elems
  const int c = e >> 10, k = e & 1023;
  const bf16* src = (k < 512) ? (Xhi + (long)c * 512 + k)
                              : (Xhi + 262144 + (long)c * 512 + (k - 512));
  *(short8*)(Pcat + e) = *(const short8*)src;
}

// ---------------------------------------------------------------------------
// Frobenius norm^2 of W1, W2 (512x512 each). ||W||_F >= sigma_max -> safe.
// ---------------------------------------------------------------------------
__global__ __launch_bounds__(256) void fnorm(const float* __restrict__ W1,
                                             const float* __restrict__ W2,
                                             float* __restrict__ sigsq) {
  const int b = blockIdx.x >> 8;
  const float4 v = *(const float4*)((b ? W2 : W1) +
                                    (((long)(blockIdx.x & 255) * 256 + threadIdx.x) << 2));
  float s = v.x * v.x + v.y * v.y + v.z * v.z + v.w * v.w;
  s = wave_sum(s);
  if ((threadIdx.x & 63) == 0) atomicAdd(&sigsq[b], s);
}

// X0 = W / ||W||_F; emit fp32 master + hi/lo splits + transposed splits.
__global__ __launch_bounds__(256) void scale_init(
    const float* __restrict__ W1, const float* __restrict__ W2,
    const float* __restrict__ sigsq, float* __restrict__ Xf,
    bf16* __restrict__ Xhi, bf16* __restrict__ Xlo,
    bf16* __restrict__ Thi, bf16* __restrict__ Tlo) {
  const long idx = (long)blockIdx.x * 256 + threadIdx.x;  // 2*262144 total
  const int b = (int)(idx >> 18);
  const int i = (int)(idx & 262143);
  const float s = rsqrtf(sigsq[b]);
  const float val = (b ? W2[i] : W1[i]) * s;
  const long o = ((long)b << 18) + i;
  Xf[o] = val;
  const bf16 h = f2b(val);
  const bf16 l = f2b(val - b2f(h));
  Xhi[o] = h; Xlo[o] = l;
  const int r = i >> 9, c = i & 511;
  const long ot = ((long)b << 18) + (long)c * 512 + r;
  Thi[ot] = h; Tlo[ot] = l;
}

// All five weight matrices fp32 -> bf16 in one launch (4 elems/thread).
// Total: 3*262144 + 2*1048576 = 2,883,584 elems -> 2816 blocks.
__global__ __launch_bounds__(256) void convert_weights(
    const float* __restrict__ Wq, const float* __restrict__ Wv,
    const float* __restrict__ Wo, const float* __restrict__ Wfc,
    const float* __restrict__ Wpr, bf16* __restrict__ Wqvb,
    bf16* __restrict__ Wob, bf16* __restrict__ Wfcb, bf16* __restrict__ Wprb) {
  const long e = ((long)blockIdx.x * 256 + threadIdx.x) << 2;
  const float* src; bf16* dst; long off;
  if (e < 262144)       { src = Wq;  dst = Wqvb;          off = e; }
  else if (e < 524288)  { src = Wv;  dst = Wqvb + 262144; off = e - 262144; }
  else if (e < 786432)  { src = Wo;  dst = Wob;           off = e - 524288; }
  else if (e < 1835008) { src = Wfc; dst = Wfcb;          off = e - 786432; }
  else                  { src = Wpr; dst = Wprb;          off = e - 1835008; }
  const float4 v = *(const float4*)(src + off);
  short4v o4;
  o4[0] = f2sb(v.x); o4[1] = f2sb(v.y); o4[2] = f2sb(v.z); o4[3] = f2sb(v.w);
  *(short4v*)(dst + off) = o4;
}

// LayerNorm over C=512, one wave per row (4 rows/block), bf16 out.
__global__ __launch_bounds__(256) void ln_rows(const float* __restrict__ x,
                                               const float* __restrict__ w,
                                               bf16* __restrict__ out) {
  const int row = (blockIdx.x << 2) + (threadIdx.x >> 6);
  const int lane = threadIdx.x & 63;
  const float* xr = x + (long)row * 512 + lane * 8;
  const float4 a = *(const float4*)xr;
  const float4 b = *(const float4*)(xr + 4);
  float v[8] = {a.x, a.y, a.z, a.w, b.x, b.y, b.z, b.w};
  float s1 = 0.f, s2 = 0.f;
#pragma unroll
  for (int i = 0; i < 8; ++i) { s1 += v[i]; s2 += v[i] * v[i]; }
  s1 = wave_allsum(s1);
  s2 = wave_allsum(s2);
  const float mean = s1 * (1.0f / 512.0f);
  const float var = s2 * (1.0f / 512.0f) - mean * mean;
  const float inv = rsqrtf(var + 1e-5f);
  const float4 w1 = *(const float4*)(w + lane * 8);
  const float4 w2 = *(const float4*)(w + lane * 8 + 4);
  const float wv[8] = {w1.x, w1.y, w1.z, w1.w, w2.x, w2.y, w2.z, w2.w};
  short8 o8;
#pragma unroll
  for (int i = 0; i < 8; ++i) o8[i] = f2sb((v[i] - mean) * inv * wv[i]);
  *(short8*)(out + (long)row * 512 + lane * 8) = o8;
}

// pscan combine: q[t] = rmsnorm(S[t]) for t >= d; one wave per row.
__global__ __launch_bounds__(256) void pscan_combine(const bf16* __restrict__ S,
                                                     bf16* __restrict__ QV, int d) {
  const int span = 4096 - d;
  const int wid = (blockIdx.x << 2) + (threadIdx.x >> 6);
  const int lane = threadIdx.x & 63;
  const int b = wid / span;
  const int tt = d + (wid - b * span);
  const long rowQ = (long)b * 4096 + tt;
  const short8 s8 = *(const short8*)(S + rowQ * 512 + lane * 8);
  float s[8]; float ss = 0.f;
#pragma unroll
  for (int i = 0; i < 8; ++i) {
    const float v = sb2f(s8[i]);
    s[i] = v; ss += v * v;
  }
  ss = wave_allsum(ss);
  const float inv = rsqrtf(ss * (1.0f / 512.0f) + 1e-6f);
  short8 o8;
#pragma unroll
  for (int i = 0; i < 8; ++i) o8[i] = f2sb(s[i] * inv);
  *(short8*)(QV + rowQ * 1024 + lane * 8) = o8;
}

// u = q * v elementwise, 8 elems/thread.
__global__ __launch_bounds__(256) void qv_mul(const bf16* __restrict__ QV,
                                              bf16* __restrict__ u) {
  const long base = ((long)blockIdx.x * 256 + threadIdx.x) << 3;
  const long row = base >> 9;
  const int c = (int)(base & 511);
  const short8 q8 = *(const short8*)(QV + row * 1024 + c);
  const short8 v8 = *(const short8*)(QV + row * 1024 + 512 + c);
  short8 o8;
#pragma unroll
  for (int i = 0; i < 8; ++i) o8[i] = f2sb(sb2f(q8[i]) * sb2f(v8[i]));
  *(short8*)(u + row * 512 + c) = o8;
}

// ---------------------------------------------------------------------------
extern "C" void kernel_launch(void* const* d_in, const int* in_sizes, int n_in,
                              void* d_out, int out_size, void* d_ws, size_t ws_size,
                              hipStream_t stream) {
  (void)in_sizes; (void)n_in; (void)out_size; (void)ws_size;
  const float* x    = (const float*)d_in[0];
  const float* ln1w = (const float*)d_in[1];
  const float* Wq   = (const float*)d_in[2];
  const float* Wv   = (const float*)d_in[3];
  const float* Wo   = (const float*)d_in[4];
  // d_in[5] = identity: provably unused (positions t<d are never updated)
  const float* Wp1  = (const float*)d_in[6];
  const float* Wp2  = (const float*)d_in[7];
  const float* ln2w = (const float*)d_in[8];
  const float* Wfc  = (const float*)d_in[9];
  const float* Wpr  = (const float*)d_in[10];
  float* out = (float*)d_out;

  const long M = 16384;
  char* ws = (char*)d_ws;
  size_t off = 0;
  auto alloc = [&](size_t bytes) -> void* {
    void* p = ws + off;
    off += (bytes + 255) & ~(size_t)255;
    return p;
  };
  bf16* YZ   = (bf16*)alloc(M * 1024 * 2);   // S uses first 16MB; +QV = h3 (64MB)
  bf16* QV   = (bf16*)alloc(M * 1024 * 2);   // 32MB
  bf16* hb   = (bf16*)alloc(M * 512 * 2);    // h -> u -> h2
  bf16* Wqvb = (bf16*)alloc(1024 * 512 * 2);
  bf16* Wob  = (bf16*)alloc(512 * 512 * 2);
  bf16* Wfcb = (bf16*)alloc(2048 * 512 * 2);
  bf16* Wprb = (bf16*)alloc(512 * 2048 * 2);
  float* Xf  = (float*)alloc(2 * 262144 * 4);
  bf16* Xhi  = (bf16*)alloc(2 * 262144 * 2);  // final P1;P2 bf16
  bf16* Xlo  = (bf16*)alloc(2 * 262144 * 2);
  bf16* XtAh = (bf16*)alloc(2 * 262144 * 2);
  bf16* XtAl = (bf16*)alloc(2 * 262144 * 2);
  bf16* XtBh = (bf16*)alloc(2 * 262144 * 2);
  bf16* XtBl = (bf16*)alloc(2 * 262144 * 2);
  bf16* Ghi  = (bf16*)alloc(2 * 262144 * 2);
  bf16* Glo  = (bf16*)alloc(2 * 262144 * 2);
  bf16* Pcat = (bf16*)alloc(512 * 1024 * 2);  // [c][P1[c,:]|P2[c,:]]
  float* sig = (float*)alloc(256);
  bf16* S  = YZ;   // [16384][512] bf16, 16MB
  bf16* h3 = YZ;   // [16384,2048] bf16 spans YZ+QV (both dead by then)

  const auto Z0 = nullptr;

  // --- polar decomposition of Wp1, Wp2 (batched Newton-Schulz, split-bf16 MFMA)
  hipMemsetAsync(sig, 0, 2 * sizeof(float), stream);
  fnorm<<<512, 256, 0, stream>>>(Wp1, Wp2, sig);
  scale_init<<<2048, 256, 0, stream>>>(Wp1, Wp2, sig, Xf, Xhi, Xlo, XtAh, XtAl);

  bf16 *tch = XtAh, *tcl = XtAl, *tnh = XtBh, *tnl = XtBl;
  const long Sz = 262144;
  for (int i = 0; i < 20; ++i) {
    const bool pol = (i >= 16);          // 16 doublings + 4 polish
    const float ac = pol ? 1.5f : 2.0f;
    const float bc = pol ? -0.5f : -1.0f;
    dim3 g(8, 8, 2);
    gemm_nt<3, true, 64><<<g, 256, 32768, stream>>>(
        Xhi, Xlo, Xhi, Xlo, 512, 512, 512, Sz, Sz, Sz,
        Z0, 0, Z0, Z0, 0.f, 0.f, Z0, Ghi, Glo, Z0, Z0);
    gemm_nt<4, true, 64><<<g, 256, 32768, stream>>>(
        Ghi, Glo, tch, tcl, 512, 512, 512, Sz, Sz, Sz,
        Z0, 0, Z0, Z0, ac, bc, Xf, Xhi, Xlo, tnh, tnl);
    bf16* sw;
    sw = tch; tch = tnh; tnh = sw;
    sw = tcl; tcl = tnl; tnl = sw;
  }
  repack_pcat<<<256, 256, 0, stream>>>(Xhi, Pcat);

  // --- weight conversions to bf16 (one launch)
  convert_weights<<<2816, 256, 0, stream>>>(Wq, Wv, Wo, Wfc, Wpr, Wqvb, Wob, Wfcb, Wprb);

  // --- SSM branch
  ln_rows<<<4096, 256, 0, stream>>>(x, ln1w, hb);
  // [q|v] = h @ [Wq;Wv]^T   (grid: x=row tiles, y=col tiles)
  gemm_nt<0, false, 128><<<dim3(128, 8, 1), 256, 32768, stream>>>(
      hb, Z0, Wqvb, Z0, 512, 512, 512, 0, 0, 0,
      QV, 1024, Z0, Z0, 0.f, 0.f, Z0, Z0, Z0, Z0, Z0);

  for (int d = 1; d < 4096; d <<= 1) {
    // S = [q[t-d]|q[t]] @ Pcat^T  (K=1024), rows [d&~127, 4096) per batch
    const int start = d & ~127;
    const int nyb = (4096 - start) >> 7;
    pscan_gemm<<<dim3(4 * nyb, 4, 1), 256, 32768, stream>>>(QV, Pcat, S, d, start, nyb);
    pscan_combine<<<4096 - d, 256, 0, stream>>>(S, QV, d);
  }

  qv_mul<<<4096, 256, 0, stream>>>(QV, hb);  // u -> hb
  // x2 = x + u @ Wo^T  -> d_out (fp32)
  gemm_nt<2, false, 128><<<dim3(128, 4, 1), 256, 32768, stream>>>(
      hb, Z0, Wob, Z0, 512, 512, 512, 0, 0, 0,
      Z0, 512, x, out, 0.f, 0.f, Z0, Z0, Z0, Z0, Z0);

  // --- MLP branch
  ln_rows<<<4096, 256, 0, stream>>>(out, ln2w, hb);  // h2 -> hb
  gemm_nt<1, false, 128><<<dim3(128, 16, 1), 256, 32768, stream>>>(
      hb, Z0, Wfcb, Z0, 512, 512, 512, 0, 0, 0,
      h3, 2048, Z0, Z0, 0.f, 0.f, Z0, Z0, Z0, Z0, Z0);
  gemm_nt<2, false, 128><<<dim3(128, 4, 1), 256, 32768, stream>>>(
      h3, Z0, Wprb, Z0, 2048, 2048, 2048, 0, 0, 0,
      Z0, 512, out, out, 0.f, 0.f, Z0, Z0, Z0, Z0, Z0);
}